// Round 10
// baseline (135.183 us; speedup 1.0000x reference)
//
#include <hip/hip_runtime.h>

typedef unsigned short u16;
typedef unsigned int u32;
typedef __attribute__((ext_vector_type(8))) __bf16 bf16x8;
typedef __attribute__((ext_vector_type(4))) float f32x4;
typedef __attribute__((ext_vector_type(16))) float f32x16;
typedef __attribute__((ext_vector_type(8))) unsigned short u16x8;
typedef __attribute__((ext_vector_type(4))) unsigned short u16x4;
typedef __attribute__((ext_vector_type(2))) unsigned int u32x2;
typedef __attribute__((ext_vector_type(4))) unsigned int u32x4;

__device__ __forceinline__ u16 f2bf(float f) {
    u32 u = __builtin_bit_cast(u32, f);
    u += 0x7fffu + ((u >> 16) & 1u);   // round-to-nearest-even
    return (u16)(u >> 16);
}

__device__ __forceinline__ float fexp2(float x) {
#if __has_builtin(__builtin_amdgcn_exp2f)
    return __builtin_amdgcn_exp2f(x);
#else
    return exp2f(x);
#endif
}

__device__ __forceinline__ float frcp(float x) {
#if __has_builtin(__builtin_amdgcn_rcpf)
    return __builtin_amdgcn_rcpf(x);
#else
    return 1.0f / x;
#endif
}

// ---------------- conversions ----------------
__global__ __launch_bounds__(256) void conv_h_kernel(const float* __restrict__ h,
                                                     u16* __restrict__ hb) {
    int i = blockIdx.x * 256 + threadIdx.x;
    float4 v = ((const float4*)h)[i];
    u16x4 o = { f2bf(v.x), f2bf(v.y), f2bf(v.z), f2bf(v.w) };
    ((u16x4*)hb)[i] = o;
}

// W [R][C] f32 -> Wt [C][R] bf16 (transpose + convert); rows < scale_rows get *scale
__global__ __launch_bounds__(256) void conv_wt_kernel(const float* __restrict__ W,
                                                      u16* __restrict__ Wt,
                                                      int R, int C,
                                                      int scale_rows, float scale) {
    __shared__ float tile[32][33];
    int t = threadIdx.x;
    int r = t >> 3, c4 = (t & 7) * 4;
    int gx = blockIdx.x * 32, gy = blockIdx.y * 32;
    float4 v = *(const float4*)&W[(size_t)(gy + r) * C + gx + c4];
    tile[r][c4 + 0] = v.x; tile[r][c4 + 1] = v.y;
    tile[r][c4 + 2] = v.z; tile[r][c4 + 3] = v.w;
    __syncthreads();
    float sc = (gx + r < scale_rows) ? scale : 1.0f;
    u16x4 o = { f2bf(tile[c4 + 0][r] * sc), f2bf(tile[c4 + 1][r] * sc),
                f2bf(tile[c4 + 2][r] * sc), f2bf(tile[c4 + 3][r] * sc) };
    *(u16x4*)&Wt[(size_t)(gx + r) * R + gy + c4] = o;
}

// ---------------- GEMM: C[M][N] = A[M][K] (bf16) x Bt[N][K]^T (bf16) ----------------
// reg-staged 2-phase, padded LDS (r5-proven structure)
template <int MODE>
__global__ __launch_bounds__(256) void gemm_bt_kernel(
        const u16* __restrict__ A, const u16* __restrict__ Bt,
        u16* __restrict__ Cb, const float* __restrict__ H, float* __restrict__ X,
        int M, int N, int K) {
    constexpr int LDT = 40;                 // 32 + 8 pad
    __shared__ u16 alds[2][128 * LDT];
    __shared__ u16 blds[2][128 * LDT];
    const int t = threadIdx.x;
    const int lane = t & 63;
    const int wave = t >> 6;
    const int wm = wave >> 1, wn = wave & 1;
    const int m0 = blockIdx.x * 128;
    const int n0 = blockIdx.y * 128;
    const int nk = K >> 5;

    const int srow = t >> 1;
    const int sch = (t & 1) * 2;
    const u16* ga = A + (size_t)(m0 + srow) * K + sch * 8;
    const u16* gb = Bt + (size_t)(n0 + srow) * K + sch * 8;
    const int wo = srow * LDT + sch * 8;

    u16x8 ra0 = *(const u16x8*)(ga);
    u16x8 ra1 = *(const u16x8*)(ga + 8);
    u16x8 rb0 = *(const u16x8*)(gb);
    u16x8 rb1 = *(const u16x8*)(gb + 8);
    *(u16x8*)&alds[0][wo] = ra0;  *(u16x8*)&alds[0][wo + 8] = ra1;
    *(u16x8*)&blds[0][wo] = rb0;  *(u16x8*)&blds[0][wo + 8] = rb1;

    f32x4 acc[4][4] = {};
    const int ko = (lane >> 4) * 8;
    const int arow_base = wm * 64 + (lane & 15);
    const int brow_base = wn * 64 + (lane & 15);

    int cur = 0;
    for (int kt = 0; kt < nk; ++kt) {
        __syncthreads();
        if (kt + 1 < nk) {
            const u16* gan = ga + (kt + 1) * 32;
            const u16* gbn = gb + (kt + 1) * 32;
            ra0 = *(const u16x8*)(gan);
            ra1 = *(const u16x8*)(gan + 8);
            rb0 = *(const u16x8*)(gbn);
            rb1 = *(const u16x8*)(gbn + 8);
        }
        bf16x8 afrag[4], bfrag[4];
#pragma unroll
        for (int m = 0; m < 4; ++m)
            afrag[m] = *(const bf16x8*)&alds[cur][(arow_base + m * 16) * LDT + ko];
#pragma unroll
        for (int n = 0; n < 4; ++n)
            bfrag[n] = *(const bf16x8*)&blds[cur][(brow_base + n * 16) * LDT + ko];
#pragma unroll
        for (int m = 0; m < 4; ++m)
#pragma unroll
            for (int n = 0; n < 4; ++n)
                acc[m][n] = __builtin_amdgcn_mfma_f32_16x16x32_bf16(afrag[m], bfrag[n],
                                                                   acc[m][n], 0, 0, 0);
        if (kt + 1 < nk) {
            *(u16x8*)&alds[cur ^ 1][wo] = ra0;  *(u16x8*)&alds[cur ^ 1][wo + 8] = ra1;
            *(u16x8*)&blds[cur ^ 1][wo] = rb0;  *(u16x8*)&blds[cur ^ 1][wo + 8] = rb1;
        }
        cur ^= 1;
    }

#pragma unroll
    for (int m = 0; m < 4; ++m)
#pragma unroll
        for (int n = 0; n < 4; ++n)
#pragma unroll
            for (int r = 0; r < 4; ++r) {
                int row = m0 + wm * 64 + m * 16 + (lane >> 4) * 4 + r;
                int col = n0 + wn * 64 + n * 16 + (lane & 15);
                size_t idx = (size_t)row * N + col;
                if (MODE == 0) Cb[idx] = f2bf(acc[m][n][r]);
                else           X[idx] = acc[m][n][r] + H[idx];
            }
}

// ---------------- V transpose ----------------
__global__ __launch_bounds__(256) void transpose_v_kernel(const u16* __restrict__ qkvb,
                                                          u16* __restrict__ vt) {
    __shared__ u16 tl[64][72];
    const int t = threadIdx.x;
    const int p = blockIdx.y;
    const int nn = p >> 1, b = p & 1;
    const int s0 = blockIdx.x * 64;
    const int r = t >> 2;
    const int ch = (t & 3) * 2;
    const u16* g = qkvb + ((size_t)(s0 + r) * 2 + b) * 3072 + 2048 + nn * 64;
    *(u16x8*)&tl[r][ch * 8]     = *(const u16x8*)(g + ch * 8);
    *(u16x8*)&tl[r][ch * 8 + 8] = *(const u16x8*)(g + ch * 8 + 8);
    __syncthreads();
    const int dh = t >> 2;
    const int sc = (t & 3) * 2;
    u16* o = vt + ((size_t)p * 64 + dh) * 2048 + s0;
#pragma unroll
    for (int q = 0; q < 2; ++q) {
        int scq = sc + q;
        u16x8 v;
#pragma unroll
        for (int j = 0; j < 8; ++j) v[j] = tl[scq * 8 + j][dh];
        *(u16x8*)(o + scq * 8) = v;
    }
}

// ---------------- causal flash attention (4 waves, 32x32 MFMA, QBLK=128) ----------
// Each wave owns 32 q-rows. Swapped QK^T with mfma_32x32x16 (exp2 units),
// in-register P exchange via permlane32_swap, defer-rescale, single-barrier
// K/V double-buffer with issue-early/write-late staging (r5-proven shell).
__global__ __launch_bounds__(256, 4) void attn_kernel(const u16* __restrict__ qkvb,
                                                      const u16* __restrict__ vt,
                                                      u16* __restrict__ attnb) {
    constexpr int LKT = 72;               // 64 + 8 pad
    __shared__ u16 kvs[2][2][64 * LKT];   // [buf][K/V]
    const int t = threadIdx.x;
    const int lane = t & 63;
    const int w = t >> 6;                 // wave 0..3, rows i0 + w*32 ..
    const int bid = blockIdx.x;
    const int g = bid >> 5;               // 0..15; heavy-first balanced pairing
    const int qt = (g < 8) ? (15 - g) : (g - 8);
    const int p = bid & 31;
    const int nn = p >> 1, b = p & 1;
    const int i0 = qt * 128;

    const int il = lane & 31;
    const int hi = lane >> 5;

    // Q fragments (B-operand): col i = il, k = kc*16 + hi*8; rows i0+w*32+il
    bf16x8 qa[4];
    {
        const u16* qg = qkvb + ((size_t)(i0 + w * 32 + il) * 2 + b) * 3072
                        + nn * 64 + hi * 8;
#pragma unroll
        for (int kc = 0; kc < 4; ++kc)
            qa[kc] = *(const bf16x8*)(qg + kc * 16);
    }

    f32x16 o[2] = {};                     // O[i=(r&3)+8(r>>2)+4hi][d=cf*32+il]
    float mrun = -3.0e38f;
    float lrun = 0.f;

    // staging geometry (256 threads cover one 64x64 K tile + V tile)
    const int srow = t >> 2;              // 0..63
    const int sch = (t & 3) * 2;
    const u16* kg = qkvb + 1024 + nn * 64 + sch * 8;
    const u16* vg = vt + ((size_t)p * 64 + srow) * 2048 + sch * 8;
    const int swo = srow * LKT + sch * 8;

    const int nt = 2 * qt + 2;
    u16x8 k0, k1, v0, v1;                 // issue-early staged regs (T14)
    {
        const u16* kgp = kg + ((size_t)srow * 2 + b) * 3072;
        k0 = *(const u16x8*)(kgp);  k1 = *(const u16x8*)(kgp + 8);
        v0 = *(const u16x8*)(vg);   v1 = *(const u16x8*)(vg + 8);
    }
    *(u16x8*)&kvs[0][0][swo] = k0;  *(u16x8*)&kvs[0][0][swo + 8] = k1;
    *(u16x8*)&kvs[0][1][swo] = v0;  *(u16x8*)&kvs[0][1][swo + 8] = v1;
    __syncthreads();

    for (int jt = 0; jt < nt; ++jt) {
        const int buf = jt & 1;
        if (jt + 1 < nt) {                // issue-early next-tile loads
            const u16* kgp = kg + ((size_t)((jt + 1) * 64 + srow) * 2 + b) * 3072;
            k0 = *(const u16x8*)(kgp);  k1 = *(const u16x8*)(kgp + 8);
            const u16* vgp = vg + (jt + 1) * 64;
            v0 = *(const u16x8*)(vgp);  v1 = *(const u16x8*)(vgp + 8);
        }

        const bool skip = (jt * 64 > i0 + w * 32 + 31);   // fully-masked subtile
        if (!skip) {
            const u16* kl = &kvs[buf][0][0];
            const u16* vl = &kvs[buf][1][0];

            // QK^T: st[jc] = S^T[j = jt*64 + jc*32 + (r&3)+8(r>>2)+4hi][i = i0+w*32+il]
            f32x16 st[2];
            __builtin_amdgcn_s_setprio(1);
#pragma unroll
            for (int jc = 0; jc < 2; ++jc) {
                f32x16 z = {};
#pragma unroll
                for (int kc = 0; kc < 4; ++kc) {
                    bf16x8 kb = *(const bf16x8*)&kl[(jc * 32 + il) * LKT + kc * 16 + hi * 8];
                    z = __builtin_amdgcn_mfma_f32_32x32x16_bf16(kb, qa[kc], z, 0, 0, 0);
                }
                st[jc] = z;
            }
            __builtin_amdgcn_s_setprio(0);

            if (jt * 64 + 63 > i0 + w * 32) {     // diagonal region: element mask
                const int iglob = i0 + w * 32 + il;
#pragma unroll
                for (int jc = 0; jc < 2; ++jc)
#pragma unroll
                    for (int r = 0; r < 16; ++r) {
                        int jglob = jt * 64 + jc * 32 + (r & 3) + 8 * (r >> 2) + 4 * hi;
                        if (jglob > iglob) st[jc][r] = -3.0e38f;
                    }
            }

            // row max: 31 in-lane + 1 shuffle (lanes {il, il+32} share row i=il)
            float mloc = st[0][0];
#pragma unroll
            for (int jc = 0; jc < 2; ++jc)
#pragma unroll
                for (int r = 0; r < 16; ++r) mloc = fmaxf(mloc, st[jc][r]);
            mloc = fmaxf(mloc, __shfl_xor(mloc, 32, 64));

            // defer-rescale (T13); o rows are i=(r&3)+8(r>>2)+4hi -> shuffle alpha
            if (__any(mloc > mrun + 8.0f)) {
                float mnew = fmaxf(mrun, mloc);
                float alpha = fexp2(mrun - mnew);
                lrun *= alpha;
                mrun = mnew;
#pragma unroll
                for (int r = 0; r < 16; ++r) {
                    float ar = __shfl(alpha, (r & 3) + 8 * (r >> 2) + 4 * hi, 64);
                    o[0][r] *= ar;
                    o[1][r] *= ar;
                }
            }

            // P = exp2(st - m), pack, exchange halves, PV
            float rsum = 0.f;
#pragma unroll
            for (int jc = 0; jc < 2; ++jc) {
                u32 W[4][2];
#pragma unroll
                for (int gg = 0; gg < 4; ++gg)
#pragma unroll
                    for (int u = 0; u < 2; ++u) {
                        float p0 = fexp2(st[jc][4 * gg + 2 * u] - mrun);
                        float p1 = fexp2(st[jc][4 * gg + 2 * u + 1] - mrun);
                        rsum += p0 + p1;
                        u32 wres;
                        asm("v_cvt_pk_bf16_f32 %0, %1, %2" : "=v"(wres) : "v"(p0), "v"(p1));
                        W[gg][u] = wres;
                    }
                // A-frag(jk): words {X'0,X'1,Y'0,Y'1}, (X'u,Y'u)=swap32(W[2jk][u],W[2jk+1][u])
                __builtin_amdgcn_s_setprio(1);
#pragma unroll
                for (int jk = 0; jk < 2; ++jk) {
                    u32x2 s0 = __builtin_amdgcn_permlane32_swap(W[2 * jk][0], W[2 * jk + 1][0], false, false);
                    u32x2 s1 = __builtin_amdgcn_permlane32_swap(W[2 * jk][1], W[2 * jk + 1][1], false, false);
                    u32x4 fw = { s0[0], s1[0], s0[1], s1[1] };
                    bf16x8 pa = __builtin_bit_cast(bf16x8, fw);
#pragma unroll
                    for (int cf = 0; cf < 2; ++cf) {
                        bf16x8 vb = *(const bf16x8*)&vl[(cf * 32 + il) * LKT
                                                        + jc * 32 + jk * 16 + hi * 8];
                        o[cf] = __builtin_amdgcn_mfma_f32_32x32x16_bf16(pa, vb, o[cf], 0, 0, 0);
                    }
                }
                __builtin_amdgcn_s_setprio(0);
            }
            rsum += __shfl_xor(rsum, 32, 64);
            lrun += rsum;
        }

        // write-late: next tile into the other buffer (last read at jt-1, safe)
        if (jt + 1 < nt) {
            *(u16x8*)&kvs[buf ^ 1][0][swo] = k0;  *(u16x8*)&kvs[buf ^ 1][0][swo + 8] = k1;
            *(u16x8*)&kvs[buf ^ 1][1][swo] = v0;  *(u16x8*)&kvs[buf ^ 1][1][swo + 8] = v1;
        }
        __syncthreads();                  // single barrier per tile-step
    }

    // ---- epilogue: normalize + store 32 rows per wave ----
    float rinv = frcp(lrun);
#pragma unroll
    for (int r = 0; r < 16; ++r) {
        int iL = (r & 3) + 8 * (r >> 2) + 4 * hi;
        float rvr = __shfl(rinv, iL, 64);
        int row = i0 + w * 32 + iL;
        u16* og = attnb + ((size_t)row * 2 + b) * 1024 + nn * 64;
#pragma unroll
        for (int cf = 0; cf < 2; ++cf)
            og[cf * 32 + il] = f2bf(o[cf][r] * rvr);
    }
}

// ---------------- residual LayerNorm ----------------
__global__ __launch_bounds__(256) void ln_kernel(const float* __restrict__ X,
                                                 const float* __restrict__ gamma,
                                                 const float* __restrict__ beta,
                                                 float* __restrict__ out) {
    __shared__ float red[8];
    const int t = threadIdx.x;
    const int row = blockIdx.x;
    float4 v = ((const float4*)(X + (size_t)row * 1024))[t];
    float s = v.x + v.y + v.z + v.w;
#pragma unroll
    for (int off = 1; off < 64; off <<= 1) s += __shfl_xor(s, off, 64);
    if ((t & 63) == 0) red[t >> 6] = s;
    __syncthreads();
    float mu = (red[0] + red[1] + red[2] + red[3]) * (1.f / 1024.f);
    float dx = v.x - mu, dy = v.y - mu, dz = v.z - mu, dw = v.w - mu;
    float q = dx * dx + dy * dy + dz * dz + dw * dw;
#pragma unroll
    for (int off = 1; off < 64; off <<= 1) q += __shfl_xor(q, off, 64);
    if ((t & 63) == 0) red[4 + (t >> 6)] = q;
    __syncthreads();
    float var = (red[4] + red[5] + red[6] + red[7]) * (1.f / 1024.f);
    float rs = rsqrtf(var + 1e-5f);
    float4 g = ((const float4*)gamma)[t];
    float4 bt = ((const float4*)beta)[t];
    float4 o;
    o.x = dx * rs * g.x + bt.x;
    o.y = dy * rs * g.y + bt.y;
    o.z = dz * rs * g.z + bt.z;
    o.w = dw * rs * g.w + bt.w;
    ((float4*)(out + (size_t)row * 1024))[t] = o;
}

// ---------------- launch ----------------
extern "C" void kernel_launch(void* const* d_in, const int* in_sizes, int n_in,
                              void* d_out, int out_size, void* d_ws, size_t ws_size,
                              hipStream_t stream) {
    const float* h     = (const float*)d_in[0];
    // d_in[1] = attn_mask (deterministic causal triu; applied analytically)
    const float* Wqkv  = (const float*)d_in[2];
    const float* Wo    = (const float*)d_in[3];
    const float* gamma = (const float*)d_in[4];
    const float* beta  = (const float*)d_in[5];
    float* out = (float*)d_out;

    char* ws = (char*)d_ws;
    u16*   hb    = (u16*)(ws);
    u16*   wqkvt = (u16*)(ws + 8388608);
    u16*   wot   = (u16*)(ws + 14680064);
    u16*   qkvb  = (u16*)(ws + 16777216);
    u16*   vt    = (u16*)(ws + 41943040);
    u16*   attnb = (u16*)(ws + 50331648);
    float* xbuf  = (float*)(ws + 58720256);

    const float qscale = 0.125f * 1.44269504088896f;  // 1/sqrt(Dh) * log2(e)

    conv_h_kernel<<<4096, 256, 0, stream>>>(h, hb);
    conv_wt_kernel<<<dim3(96, 32), 256, 0, stream>>>(Wqkv, wqkvt, 1024, 3072, 1024, qscale);
    conv_wt_kernel<<<dim3(32, 32), 256, 0, stream>>>(Wo, wot, 1024, 1024, 0, 1.0f);
    gemm_bt_kernel<0><<<dim3(32, 24), 256, 0, stream>>>(hb, wqkvt, qkvb, nullptr, nullptr,
                                                        4096, 3072, 1024);
    transpose_v_kernel<<<dim3(32, 32), 256, 0, stream>>>(qkvb, vt);
    attn_kernel<<<512, 256, 0, stream>>>(qkvb, vt, attnb);
    gemm_bt_kernel<1><<<dim3(32, 8), 256, 0, stream>>>(attnb, wot, nullptr, h, xbuf,
                                                       4096, 1024, 1024);
    ln_kernel<<<4096, 256, 0, stream>>>(xbuf, gamma, beta, out);
}

// Round 11
// 124.796 us; speedup vs baseline: 1.0832x; 1.0832x over previous
//
#include <hip/hip_runtime.h>

typedef unsigned short u16;
typedef unsigned int u32;
typedef __attribute__((ext_vector_type(8))) __bf16 bf16x8;
typedef __attribute__((ext_vector_type(4))) float f32x4;
typedef __attribute__((ext_vector_type(16))) float f32x16;
typedef __attribute__((ext_vector_type(8))) unsigned short u16x8;
typedef __attribute__((ext_vector_type(4))) unsigned short u16x4;
typedef __attribute__((ext_vector_type(2))) unsigned int u32x2;
typedef __attribute__((ext_vector_type(4))) unsigned int u32x4;

__device__ __forceinline__ u16 f2bf(float f) {
    u32 u = __builtin_bit_cast(u32, f);
    u += 0x7fffu + ((u >> 16) & 1u);   // round-to-nearest-even
    return (u16)(u >> 16);
}

__device__ __forceinline__ float fexp2(float x) {
#if __has_builtin(__builtin_amdgcn_exp2f)
    return __builtin_amdgcn_exp2f(x);
#else
    return exp2f(x);
#endif
}

__device__ __forceinline__ float frcp(float x) {
#if __has_builtin(__builtin_amdgcn_rcpf)
    return __builtin_amdgcn_rcpf(x);
#else
    return 1.0f / x;
#endif
}

// ---------------- conversions ----------------
__global__ __launch_bounds__(256) void conv_h_kernel(const float* __restrict__ h,
                                                     u16* __restrict__ hb) {
    int i = blockIdx.x * 256 + threadIdx.x;
    float4 v = ((const float4*)h)[i];
    u16x4 o = { f2bf(v.x), f2bf(v.y), f2bf(v.z), f2bf(v.w) };
    ((u16x4*)hb)[i] = o;
}

// W [R][C] f32 -> Wt [C][R] bf16 (transpose + convert); rows < scale_rows get *scale
__global__ __launch_bounds__(256) void conv_wt_kernel(const float* __restrict__ W,
                                                      u16* __restrict__ Wt,
                                                      int R, int C,
                                                      int scale_rows, float scale) {
    __shared__ float tile[32][33];
    int t = threadIdx.x;
    int r = t >> 3, c4 = (t & 7) * 4;
    int gx = blockIdx.x * 32, gy = blockIdx.y * 32;
    float4 v = *(const float4*)&W[(size_t)(gy + r) * C + gx + c4];
    tile[r][c4 + 0] = v.x; tile[r][c4 + 1] = v.y;
    tile[r][c4 + 2] = v.z; tile[r][c4 + 3] = v.w;
    __syncthreads();
    float sc = (gx + r < scale_rows) ? scale : 1.0f;
    u16x4 o = { f2bf(tile[c4 + 0][r] * sc), f2bf(tile[c4 + 1][r] * sc),
                f2bf(tile[c4 + 2][r] * sc), f2bf(tile[c4 + 3][r] * sc) };
    *(u16x4*)&Wt[(size_t)(gx + r) * R + gy + c4] = o;
}

// ---------------- GEMM: C[M][N] = A[M][K] (bf16) x Bt[N][K]^T (bf16) ----------------
// reg-staged 2-phase, padded LDS (r5-proven structure)
template <int MODE>
__global__ __launch_bounds__(256) void gemm_bt_kernel(
        const u16* __restrict__ A, const u16* __restrict__ Bt,
        u16* __restrict__ Cb, const float* __restrict__ H, float* __restrict__ X,
        int M, int N, int K) {
    constexpr int LDT = 40;                 // 32 + 8 pad
    __shared__ u16 alds[2][128 * LDT];
    __shared__ u16 blds[2][128 * LDT];
    const int t = threadIdx.x;
    const int lane = t & 63;
    const int wave = t >> 6;
    const int wm = wave >> 1, wn = wave & 1;
    const int m0 = blockIdx.x * 128;
    const int n0 = blockIdx.y * 128;
    const int nk = K >> 5;

    const int srow = t >> 1;
    const int sch = (t & 1) * 2;
    const u16* ga = A + (size_t)(m0 + srow) * K + sch * 8;
    const u16* gb = Bt + (size_t)(n0 + srow) * K + sch * 8;
    const int wo = srow * LDT + sch * 8;

    u16x8 ra0 = *(const u16x8*)(ga);
    u16x8 ra1 = *(const u16x8*)(ga + 8);
    u16x8 rb0 = *(const u16x8*)(gb);
    u16x8 rb1 = *(const u16x8*)(gb + 8);
    *(u16x8*)&alds[0][wo] = ra0;  *(u16x8*)&alds[0][wo + 8] = ra1;
    *(u16x8*)&blds[0][wo] = rb0;  *(u16x8*)&blds[0][wo + 8] = rb1;

    f32x4 acc[4][4] = {};
    const int ko = (lane >> 4) * 8;
    const int arow_base = wm * 64 + (lane & 15);
    const int brow_base = wn * 64 + (lane & 15);

    int cur = 0;
    for (int kt = 0; kt < nk; ++kt) {
        __syncthreads();
        if (kt + 1 < nk) {
            const u16* gan = ga + (kt + 1) * 32;
            const u16* gbn = gb + (kt + 1) * 32;
            ra0 = *(const u16x8*)(gan);
            ra1 = *(const u16x8*)(gan + 8);
            rb0 = *(const u16x8*)(gbn);
            rb1 = *(const u16x8*)(gbn + 8);
        }
        bf16x8 afrag[4], bfrag[4];
#pragma unroll
        for (int m = 0; m < 4; ++m)
            afrag[m] = *(const bf16x8*)&alds[cur][(arow_base + m * 16) * LDT + ko];
#pragma unroll
        for (int n = 0; n < 4; ++n)
            bfrag[n] = *(const bf16x8*)&blds[cur][(brow_base + n * 16) * LDT + ko];
#pragma unroll
        for (int m = 0; m < 4; ++m)
#pragma unroll
            for (int n = 0; n < 4; ++n)
                acc[m][n] = __builtin_amdgcn_mfma_f32_16x16x32_bf16(afrag[m], bfrag[n],
                                                                   acc[m][n], 0, 0, 0);
        if (kt + 1 < nk) {
            *(u16x8*)&alds[cur ^ 1][wo] = ra0;  *(u16x8*)&alds[cur ^ 1][wo + 8] = ra1;
            *(u16x8*)&blds[cur ^ 1][wo] = rb0;  *(u16x8*)&blds[cur ^ 1][wo + 8] = rb1;
        }
        cur ^= 1;
    }

#pragma unroll
    for (int m = 0; m < 4; ++m)
#pragma unroll
        for (int n = 0; n < 4; ++n)
#pragma unroll
            for (int r = 0; r < 4; ++r) {
                int row = m0 + wm * 64 + m * 16 + (lane >> 4) * 4 + r;
                int col = n0 + wn * 64 + n * 16 + (lane & 15);
                size_t idx = (size_t)row * N + col;
                if (MODE == 0) Cb[idx] = f2bf(acc[m][n][r]);
                else           X[idx] = acc[m][n][r] + H[idx];
            }
}

// ---------------- V transpose ----------------
__global__ __launch_bounds__(256) void transpose_v_kernel(const u16* __restrict__ qkvb,
                                                          u16* __restrict__ vt) {
    __shared__ u16 tl[64][72];
    const int t = threadIdx.x;
    const int p = blockIdx.y;
    const int nn = p >> 1, b = p & 1;
    const int s0 = blockIdx.x * 64;
    const int r = t >> 2;
    const int ch = (t & 3) * 2;
    const u16* g = qkvb + ((size_t)(s0 + r) * 2 + b) * 3072 + 2048 + nn * 64;
    *(u16x8*)&tl[r][ch * 8]     = *(const u16x8*)(g + ch * 8);
    *(u16x8*)&tl[r][ch * 8 + 8] = *(const u16x8*)(g + ch * 8 + 8);
    __syncthreads();
    const int dh = t >> 2;
    const int sc = (t & 3) * 2;
    u16* o = vt + ((size_t)p * 64 + dh) * 2048 + s0;
#pragma unroll
    for (int q = 0; q < 2; ++q) {
        int scq = sc + q;
        u16x8 v;
#pragma unroll
        for (int j = 0; j < 8; ++j) v[j] = tl[scq * 8 + j][dh];
        *(u16x8*)(o + scq * 8) = v;
    }
}

// ---------------- causal flash attention (4 waves, 32x32 MFMA, QBLK=128) ----------
// Each wave owns 32 q-rows. Swapped QK^T with mfma_32x32x16 (exp2 units),
// in-register P exchange via permlane32_swap, defer-rescale, single-barrier
// K/V double-buffer with issue-early/write-late staging.
// __launch_bounds__(256, 2): 2 waves/EU min -> total reg cap 256/lane (no spill;
// the f32x16 o[2]+st[2] need 64 regs alone — w=4's 128 cap forced the r9/r10 spills).
__global__ __launch_bounds__(256, 2) void attn_kernel(const u16* __restrict__ qkvb,
                                                      const u16* __restrict__ vt,
                                                      u16* __restrict__ attnb) {
    constexpr int LKT = 72;               // 64 + 8 pad
    __shared__ u16 kvs[2][2][64 * LKT];   // [buf][K/V]
    const int t = threadIdx.x;
    const int lane = t & 63;
    const int w = t >> 6;                 // wave 0..3, rows i0 + w*32 ..
    const int bid = blockIdx.x;
    const int g = bid >> 5;               // 0..15; heavy-first balanced pairing
    const int qt = (g < 8) ? (15 - g) : (g - 8);
    const int p = bid & 31;
    const int nn = p >> 1, b = p & 1;
    const int i0 = qt * 128;

    const int il = lane & 31;
    const int hi = lane >> 5;

    // Q fragments (B-operand): col i = il, k = kc*16 + hi*8; rows i0+w*32+il
    bf16x8 qa[4];
    {
        const u16* qg = qkvb + ((size_t)(i0 + w * 32 + il) * 2 + b) * 3072
                        + nn * 64 + hi * 8;
#pragma unroll
        for (int kc = 0; kc < 4; ++kc)
            qa[kc] = *(const bf16x8*)(qg + kc * 16);
    }

    f32x16 o[2] = {};                     // O[i=(r&3)+8(r>>2)+4hi][d=cf*32+il]
    float mrun = -3.0e38f;
    float lrun = 0.f;

    // staging geometry (256 threads cover one 64x64 K tile + V tile)
    const int srow = t >> 2;              // 0..63
    const int sch = (t & 3) * 2;
    const u16* kg = qkvb + 1024 + nn * 64 + sch * 8;
    const u16* vg = vt + ((size_t)p * 64 + srow) * 2048 + sch * 8;
    const int swo = srow * LKT + sch * 8;

    const int nt = 2 * qt + 2;
    u16x8 k0, k1, v0, v1;                 // issue-early staged regs (T14)
    {
        const u16* kgp = kg + ((size_t)srow * 2 + b) * 3072;
        k0 = *(const u16x8*)(kgp);  k1 = *(const u16x8*)(kgp + 8);
        v0 = *(const u16x8*)(vg);   v1 = *(const u16x8*)(vg + 8);
    }
    *(u16x8*)&kvs[0][0][swo] = k0;  *(u16x8*)&kvs[0][0][swo + 8] = k1;
    *(u16x8*)&kvs[0][1][swo] = v0;  *(u16x8*)&kvs[0][1][swo + 8] = v1;
    __syncthreads();

    for (int jt = 0; jt < nt; ++jt) {
        const int buf = jt & 1;
        if (jt + 1 < nt) {                // issue-early next-tile loads
            const u16* kgp = kg + ((size_t)((jt + 1) * 64 + srow) * 2 + b) * 3072;
            k0 = *(const u16x8*)(kgp);  k1 = *(const u16x8*)(kgp + 8);
            const u16* vgp = vg + (jt + 1) * 64;
            v0 = *(const u16x8*)(vgp);  v1 = *(const u16x8*)(vgp + 8);
        }

        const bool skip = (jt * 64 > i0 + w * 32 + 31);   // fully-masked subtile
        if (!skip) {
            const u16* kl = &kvs[buf][0][0];
            const u16* vl = &kvs[buf][1][0];

            // QK^T: st[jc] = S^T[j = jt*64 + jc*32 + (r&3)+8(r>>2)+4hi][i = i0+w*32+il]
            f32x16 st[2];
            __builtin_amdgcn_s_setprio(1);
#pragma unroll
            for (int jc = 0; jc < 2; ++jc) {
                f32x16 z = {};
#pragma unroll
                for (int kc = 0; kc < 4; ++kc) {
                    bf16x8 kb = *(const bf16x8*)&kl[(jc * 32 + il) * LKT + kc * 16 + hi * 8];
                    z = __builtin_amdgcn_mfma_f32_32x32x16_bf16(kb, qa[kc], z, 0, 0, 0);
                }
                st[jc] = z;
            }
            __builtin_amdgcn_s_setprio(0);

            if (jt * 64 + 63 > i0 + w * 32) {     // diagonal region: element mask
                const int iglob = i0 + w * 32 + il;
#pragma unroll
                for (int jc = 0; jc < 2; ++jc)
#pragma unroll
                    for (int r = 0; r < 16; ++r) {
                        int jglob = jt * 64 + jc * 32 + (r & 3) + 8 * (r >> 2) + 4 * hi;
                        if (jglob > iglob) st[jc][r] = -3.0e38f;
                    }
            }

            // row max: 31 in-lane + 1 shuffle (lanes {il, il+32} share row i=il)
            float mloc = st[0][0];
#pragma unroll
            for (int jc = 0; jc < 2; ++jc)
#pragma unroll
                for (int r = 0; r < 16; ++r) mloc = fmaxf(mloc, st[jc][r]);
            mloc = fmaxf(mloc, __shfl_xor(mloc, 32, 64));

            // defer-rescale (T13); o rows are i=(r&3)+8(r>>2)+4hi -> shuffle alpha
            if (__any(mloc > mrun + 8.0f)) {
                float mnew = fmaxf(mrun, mloc);
                float alpha = fexp2(mrun - mnew);
                lrun *= alpha;
                mrun = mnew;
#pragma unroll
                for (int r = 0; r < 16; ++r) {
                    float ar = __shfl(alpha, (r & 3) + 8 * (r >> 2) + 4 * hi, 64);
                    o[0][r] *= ar;
                    o[1][r] *= ar;
                }
            }

            // P = exp2(st - m), pack, exchange halves, PV
            float rsum = 0.f;
#pragma unroll
            for (int jc = 0; jc < 2; ++jc) {
                u32 W[4][2];
#pragma unroll
                for (int gg = 0; gg < 4; ++gg)
#pragma unroll
                    for (int u = 0; u < 2; ++u) {
                        float p0 = fexp2(st[jc][4 * gg + 2 * u] - mrun);
                        float p1 = fexp2(st[jc][4 * gg + 2 * u + 1] - mrun);
                        rsum += p0 + p1;
                        u32 wres;
                        asm("v_cvt_pk_bf16_f32 %0, %1, %2" : "=v"(wres) : "v"(p0), "v"(p1));
                        W[gg][u] = wres;
                    }
                // A-frag(jk): words {X'0,X'1,Y'0,Y'1}, (X'u,Y'u)=swap32(W[2jk][u],W[2jk+1][u])
                __builtin_amdgcn_s_setprio(1);
#pragma unroll
                for (int jk = 0; jk < 2; ++jk) {
                    u32x2 s0 = __builtin_amdgcn_permlane32_swap(W[2 * jk][0], W[2 * jk + 1][0], false, false);
                    u32x2 s1 = __builtin_amdgcn_permlane32_swap(W[2 * jk][1], W[2 * jk + 1][1], false, false);
                    u32x4 fw = { s0[0], s1[0], s0[1], s1[1] };
                    bf16x8 pa = __builtin_bit_cast(bf16x8, fw);
#pragma unroll
                    for (int cf = 0; cf < 2; ++cf) {
                        bf16x8 vb = *(const bf16x8*)&vl[(cf * 32 + il) * LKT
                                                        + jc * 32 + jk * 16 + hi * 8];
                        o[cf] = __builtin_amdgcn_mfma_f32_32x32x16_bf16(pa, vb, o[cf], 0, 0, 0);
                    }
                }
                __builtin_amdgcn_s_setprio(0);
            }
            rsum += __shfl_xor(rsum, 32, 64);
            lrun += rsum;
        }

        // write-late: next tile into the other buffer (last read at jt-1, safe)
        if (jt + 1 < nt) {
            *(u16x8*)&kvs[buf ^ 1][0][swo] = k0;  *(u16x8*)&kvs[buf ^ 1][0][swo + 8] = k1;
            *(u16x8*)&kvs[buf ^ 1][1][swo] = v0;  *(u16x8*)&kvs[buf ^ 1][1][swo + 8] = v1;
        }
        __syncthreads();                  // single barrier per tile-step
    }

    // ---- epilogue: normalize + store 32 rows per wave ----
    float rinv = frcp(lrun);
#pragma unroll
    for (int r = 0; r < 16; ++r) {
        int iL = (r & 3) + 8 * (r >> 2) + 4 * hi;
        float rvr = __shfl(rinv, iL, 64);
        int row = i0 + w * 32 + iL;
        u16* og = attnb + ((size_t)row * 2 + b) * 1024 + nn * 64;
#pragma unroll
        for (int cf = 0; cf < 2; ++cf)
            og[cf * 32 + il] = f2bf(o[cf][r] * rvr);
    }
}

// ---------------- residual LayerNorm ----------------
__global__ __launch_bounds__(256) void ln_kernel(const float* __restrict__ X,
                                                 const float* __restrict__ gamma,
                                                 const float* __restrict__ beta,
                                                 float* __restrict__ out) {
    __shared__ float red[8];
    const int t = threadIdx.x;
    const int row = blockIdx.x;
    float4 v = ((const float4*)(X + (size_t)row * 1024))[t];
    float s = v.x + v.y + v.z + v.w;
#pragma unroll
    for (int off = 1; off < 64; off <<= 1) s += __shfl_xor(s, off, 64);
    if ((t & 63) == 0) red[t >> 6] = s;
    __syncthreads();
    float mu = (red[0] + red[1] + red[2] + red[3]) * (1.f / 1024.f);
    float dx = v.x - mu, dy = v.y - mu, dz = v.z - mu, dw = v.w - mu;
    float q = dx * dx + dy * dy + dz * dz + dw * dw;
#pragma unroll
    for (int off = 1; off < 64; off <<= 1) q += __shfl_xor(q, off, 64);
    if ((t & 63) == 0) red[4 + (t >> 6)] = q;
    __syncthreads();
    float var = (red[4] + red[5] + red[6] + red[7]) * (1.f / 1024.f);
    float rs = rsqrtf(var + 1e-5f);
    float4 g = ((const float4*)gamma)[t];
    float4 bt = ((const float4*)beta)[t];
    float4 o;
    o.x = dx * rs * g.x + bt.x;
    o.y = dy * rs * g.y + bt.y;
    o.z = dz * rs * g.z + bt.z;
    o.w = dw * rs * g.w + bt.w;
    ((float4*)(out + (size_t)row * 1024))[t] = o;
}

// ---------------- launch ----------------
extern "C" void kernel_launch(void* const* d_in, const int* in_sizes, int n_in,
                              void* d_out, int out_size, void* d_ws, size_t ws_size,
                              hipStream_t stream) {
    const float* h     = (const float*)d_in[0];
    // d_in[1] = attn_mask (deterministic causal triu; applied analytically)
    const float* Wqkv  = (const float*)d_in[2];
    const float* Wo    = (const float*)d_in[3];
    const float* gamma = (const float*)d_in[4];
    const float* beta  = (const float*)d_in[5];
    float* out = (float*)d_out;

    char* ws = (char*)d_ws;
    u16*   hb    = (u16*)(ws);
    u16*   wqkvt = (u16*)(ws + 8388608);
    u16*   wot   = (u16*)(ws + 14680064);
    u16*   qkvb  = (u16*)(ws + 16777216);
    u16*   vt    = (u16*)(ws + 41943040);
    u16*   attnb = (u16*)(ws + 50331648);
    float* xbuf  = (float*)(ws + 58720256);

    const float qscale = 0.125f * 1.44269504088896f;  // 1/sqrt(Dh) * log2(e)

    conv_h_kernel<<<4096, 256, 0, stream>>>(h, hb);
    conv_wt_kernel<<<dim3(96, 32), 256, 0, stream>>>(Wqkv, wqkvt, 1024, 3072, 1024, qscale);
    conv_wt_kernel<<<dim3(32, 32), 256, 0, stream>>>(Wo, wot, 1024, 1024, 0, 1.0f);
    gemm_bt_kernel<0><<<dim3(32, 24), 256, 0, stream>>>(hb, wqkvt, qkvb, nullptr, nullptr,
                                                        4096, 3072, 1024);
    transpose_v_kernel<<<dim3(32, 32), 256, 0, stream>>>(qkvb, vt);
    attn_kernel<<<512, 256, 0, stream>>>(qkvb, vt, attnb);
    gemm_bt_kernel<1><<<dim3(32, 8), 256, 0, stream>>>(attnb, wot, nullptr, h, xbuf,
                                                       4096, 1024, 1024);
    ln_kernel<<<4096, 256, 0, stream>>>(xbuf, gamma, beta, out);
}

// Round 12
// 124.651 us; speedup vs baseline: 1.0845x; 1.0012x over previous
//
#include <hip/hip_runtime.h>

typedef unsigned short u16;
typedef unsigned int u32;
typedef __attribute__((ext_vector_type(8))) __bf16 bf16x8;
typedef __attribute__((ext_vector_type(4))) float f32x4;
typedef __attribute__((ext_vector_type(8))) unsigned short u16x8;
typedef __attribute__((ext_vector_type(4))) unsigned short u16x4;
typedef __attribute__((ext_vector_type(2))) unsigned int u32x2;
typedef __attribute__((ext_vector_type(4))) unsigned int u32x4;

#if defined(__has_builtin)
#if __has_builtin(__builtin_amdgcn_permlane32_swap) && __has_builtin(__builtin_amdgcn_permlane16_swap)
#define USE_PERMLANE 1
#endif
#endif
#ifndef USE_PERMLANE
#define USE_PERMLANE 0
#endif

__device__ __forceinline__ u16 f2bf(float f) {
    u32 u = __builtin_bit_cast(u32, f);
    u += 0x7fffu + ((u >> 16) & 1u);   // round-to-nearest-even
    return (u16)(u >> 16);
}

__device__ __forceinline__ float fexp2(float x) {
#if __has_builtin(__builtin_amdgcn_exp2f)
    return __builtin_amdgcn_exp2f(x);
#else
    return exp2f(x);
#endif
}

__device__ __forceinline__ float frcp(float x) {
#if __has_builtin(__builtin_amdgcn_rcpf)
    return __builtin_amdgcn_rcpf(x);
#else
    return 1.0f / x;
#endif
}

#define GL16(gp, lp) __builtin_amdgcn_global_load_lds(                           \
    (const __attribute__((address_space(1))) void*)(gp),                          \
    (__attribute__((address_space(3))) void*)(lp), 16, 0, 0)

// ---------------- conversions ----------------
__global__ __launch_bounds__(256) void conv_h_kernel(const float* __restrict__ h,
                                                     u16* __restrict__ hb) {
    int i = blockIdx.x * 256 + threadIdx.x;
    float4 v = ((const float4*)h)[i];
    u16x4 o = { f2bf(v.x), f2bf(v.y), f2bf(v.z), f2bf(v.w) };
    ((u16x4*)hb)[i] = o;
}

// W [R][C] f32 -> Wt [C][R] bf16 (transpose + convert); rows < scale_rows get *scale
__global__ __launch_bounds__(256) void conv_wt_kernel(const float* __restrict__ W,
                                                      u16* __restrict__ Wt,
                                                      int R, int C,
                                                      int scale_rows, float scale) {
    __shared__ float tile[32][33];
    int t = threadIdx.x;
    int r = t >> 3, c4 = (t & 7) * 4;
    int gx = blockIdx.x * 32, gy = blockIdx.y * 32;
    float4 v = *(const float4*)&W[(size_t)(gy + r) * C + gx + c4];
    tile[r][c4 + 0] = v.x; tile[r][c4 + 1] = v.y;
    tile[r][c4 + 2] = v.z; tile[r][c4 + 3] = v.w;
    __syncthreads();
    float sc = (gx + r < scale_rows) ? scale : 1.0f;
    u16x4 o = { f2bf(tile[c4 + 0][r] * sc), f2bf(tile[c4 + 1][r] * sc),
                f2bf(tile[c4 + 2][r] * sc), f2bf(tile[c4 + 3][r] * sc) };
    *(u16x4*)&Wt[(size_t)(gx + r) * R + gy + c4] = o;
}

// ============ gemm1: 8-phase 256x256xBK64, counted vmcnt, gload_lds ============
// C[M][N] = A[M][K] x Bt[N][K]^T, bf16 out. 512 thr, 8 waves (2M x 4N).
// LDS [buf][ks-half][256 rows][32 u16], half = 16KB contiguous staging granule.
// Slot-XOR swizzle (slot ^= row&3) applied to SOURCE lanes + reads (dest linear).
// Stage ledger: P1:B1.A.ks1(2i+1) P2:B1.B.ks1 P3:B0.A.ks0(2i+2) P4:B0.B.ks0+vmcnt(4)
//               P5:B0.A.ks1 P6:B0.B.ks1 P7:B1.A.ks0(2i+3) P8:B1.B.ks0+vmcnt(4)
// Every half has >=1 vmcnt(4) between land-guarantee and first read; 2 half-tiles
// (4 loads/wave) stay in flight across each wait — never drains to 0.
__global__ __launch_bounds__(512, 2) void gemm1_8ph_kernel(
        const u16* __restrict__ A, const u16* __restrict__ Bt,
        u16* __restrict__ Cb, int M, int N, int K) {
    __shared__ u16 alds[2][2][8192];   // [buf][ks][row*32 + col]
    __shared__ u16 blds[2][2][8192];
    const int t = threadIdx.x;
    const int lane = t & 63;
    const int wave = t >> 6;           // 0..7
    const int wm = wave >> 2;          // 0..1
    const int wn = wave & 3;           // 0..3
    const int li = lane & 15, lg = lane >> 4;

    const int nwg = (int)gridDim.x;    // 192 (%8==0)
    const int lin = (int)blockIdx.x;
    const int swz = (lin & 7) * (nwg >> 3) + (lin >> 3);
    const int mt = M >> 8;
    const int m0 = (swz % mt) << 8;
    const int n0 = (swz / mt) << 8;

    // staging: wave covers instrs {2w,2w+1} of each 16KB half (16 rows x 64B each).
    // lane l -> row (l>>2), src slot ((l&3) ^ ((l>>2)&3)) [inverse swizzle, row base %4==0]
    const int srow = lane >> 2;
    const int sslot = ((lane & 3) ^ ((lane >> 2) & 3)) * 8;   // u16
    const u16* gAb = A + (size_t)(m0 + wave * 32 + srow) * K + sslot;
    const u16* gBb = Bt + (size_t)(n0 + wave * 32 + srow) * K + sslot;
    const int ldst = wave * 1024;      // u16 offset of instr q=0; q=1 adds 512

#define STAGE_A1(buf, ks, kt)                                                    \
    { GL16(gAb + (size_t)(kt) * 64 + (ks) * 32, &alds[buf][ks][ldst]);           \
      GL16(gAb + (size_t)16 * K + (size_t)(kt) * 64 + (ks) * 32,                 \
           &alds[buf][ks][ldst + 512]); }
#define STAGE_B1(buf, ks, kt)                                                    \
    { GL16(gBb + (size_t)(kt) * 64 + (ks) * 32, &blds[buf][ks][ldst]);           \
      GL16(gBb + (size_t)16 * K + (size_t)(kt) * 64 + (ks) * 32,                 \
           &blds[buf][ks][ldst + 512]); }

    // swizzled fragment reads: row base (mult of 16) + li -> slot lg ^ (li&3)
    const int rslot = (lg ^ (li & 3)) * 8;
#define READ_A(buf, ks, mh)                                                      \
    _Pragma("unroll") for (int m = 0; m < 4; ++m)                                \
        af[m] = *(const bf16x8*)&alds[buf][ks][(wm * 128 + (mh) * 64 + m * 16 + li) * 32 + rslot];
#define READ_B(buf, ks)                                                          \
    _Pragma("unroll") for (int n = 0; n < 4; ++n)                                \
        bfr[n] = *(const bf16x8*)&blds[buf][ks][(wn * 64 + n * 16 + li) * 32 + rslot];
#define MFMA16(mh)                                                               \
    _Pragma("unroll") for (int m = 0; m < 4; ++m)                                \
        _Pragma("unroll") for (int n = 0; n < 4; ++n)                            \
            acc[(mh) * 4 + m][n] = __builtin_amdgcn_mfma_f32_16x16x32_bf16(      \
                af[m], bfr[n], acc[(mh) * 4 + m][n], 0, 0, 0);

#define PH_BAR() __builtin_amdgcn_s_barrier()
#define PH_MFMA(mh)                                                              \
    PH_BAR();                                                                    \
    __builtin_amdgcn_s_setprio(1); MFMA16(mh); __builtin_amdgcn_s_setprio(0);    \
    PH_BAR();
#define VMCNT4() asm volatile("s_waitcnt vmcnt(4)" ::: "memory")

    f32x4 acc[8][4] = {};
    bf16x8 af[4], bfr[4];

    // prologue: tile0 -> buf0 (4 halves), tile1.ks0 -> buf1 (2 halves) = 12 loads
    STAGE_A1(0, 0, 0); STAGE_B1(0, 0, 0);
    STAGE_A1(0, 1, 0); STAGE_B1(0, 1, 0);
    STAGE_A1(1, 0, 1); STAGE_B1(1, 0, 1);
    VMCNT4();                          // tile0 fully landed (tile1.ks0 in flight)
    PH_BAR();

    const int NIT = K >> 7;            // 8 iterations, 2 K-tiles each
    for (int i = 0; i < NIT; ++i) {
        const int t1 = 2 * i + 1, t2 = 2 * i + 2, t3 = 2 * i + 3;
        const bool more = (i + 1 < NIT);
        // P1: buf0.ks0.mh0
        READ_A(0, 0, 0); READ_B(0, 0);
        STAGE_A1(1, 1, t1);
        PH_MFMA(0);
        // P2: buf0.ks0.mh1
        READ_A(0, 0, 1);
        STAGE_B1(1, 1, t1);
        PH_MFMA(1);
        // P3: buf0.ks1.mh0
        READ_A(0, 1, 0); READ_B(0, 1);
        if (more) STAGE_A1(0, 0, t2);
        PH_MFMA(0);
        // P4: buf0.ks1.mh1  + vmcnt(4)
        READ_A(0, 1, 1);
        if (more) STAGE_B1(0, 0, t2);
        VMCNT4();
        PH_MFMA(1);
        // P5: buf1.ks0.mh0
        READ_A(1, 0, 0); READ_B(1, 0);
        if (more) STAGE_A1(0, 1, t2);
        PH_MFMA(0);
        // P6: buf1.ks0.mh1
        READ_A(1, 0, 1);
        if (more) STAGE_B1(0, 1, t2);
        PH_MFMA(1);
        // P7: buf1.ks1.mh0
        READ_A(1, 1, 0); READ_B(1, 1);
        if (more) STAGE_A1(1, 0, t3);
        PH_MFMA(0);
        // P8: buf1.ks1.mh1  + vmcnt(4)
        READ_A(1, 1, 1);
        if (more) STAGE_B1(1, 0, t3);
        VMCNT4();
        PH_MFMA(1);
    }

    // epilogue: bf16 C-write (proven mapping)
#pragma unroll
    for (int mr = 0; mr < 8; ++mr)
#pragma unroll
        for (int nr = 0; nr < 4; ++nr)
#pragma unroll
            for (int rr = 0; rr < 4; ++rr) {
                int row = m0 + wm * 128 + mr * 16 + lg * 4 + rr;
                int col = n0 + wn * 64 + nr * 16 + li;
                Cb[(size_t)row * N + col] = f2bf(acc[mr][nr][rr]);
            }
#undef STAGE_A1
#undef STAGE_B1
#undef READ_A
#undef READ_B
#undef MFMA16
#undef PH_BAR
#undef PH_MFMA
#undef VMCNT4
}

// ---------------- GEMM (128², reg-staged 2-phase) — used for gemm2 ----------------
template <int MODE>
__global__ __launch_bounds__(256) void gemm_bt_kernel(
        const u16* __restrict__ A, const u16* __restrict__ Bt,
        u16* __restrict__ Cb, const float* __restrict__ H, float* __restrict__ X,
        int M, int N, int K) {
    constexpr int LDT = 40;                 // 32 + 8 pad
    __shared__ u16 alds[2][128 * LDT];
    __shared__ u16 blds[2][128 * LDT];
    const int t = threadIdx.x;
    const int lane = t & 63;
    const int wave = t >> 6;
    const int wm = wave >> 1, wn = wave & 1;
    const int m0 = blockIdx.x * 128;
    const int n0 = blockIdx.y * 128;
    const int nk = K >> 5;

    const int srow = t >> 1;
    const int sch = (t & 1) * 2;
    const u16* ga = A + (size_t)(m0 + srow) * K + sch * 8;
    const u16* gb = Bt + (size_t)(n0 + srow) * K + sch * 8;
    const int wo = srow * LDT + sch * 8;

    u16x8 ra0 = *(const u16x8*)(ga);
    u16x8 ra1 = *(const u16x8*)(ga + 8);
    u16x8 rb0 = *(const u16x8*)(gb);
    u16x8 rb1 = *(const u16x8*)(gb + 8);
    *(u16x8*)&alds[0][wo] = ra0;  *(u16x8*)&alds[0][wo + 8] = ra1;
    *(u16x8*)&blds[0][wo] = rb0;  *(u16x8*)&blds[0][wo + 8] = rb1;

    f32x4 acc[4][4] = {};
    const int ko = (lane >> 4) * 8;
    const int arow_base = wm * 64 + (lane & 15);
    const int brow_base = wn * 64 + (lane & 15);

    int cur = 0;
    for (int kt = 0; kt < nk; ++kt) {
        __syncthreads();
        if (kt + 1 < nk) {
            const u16* gan = ga + (kt + 1) * 32;
            const u16* gbn = gb + (kt + 1) * 32;
            ra0 = *(const u16x8*)(gan);
            ra1 = *(const u16x8*)(gan + 8);
            rb0 = *(const u16x8*)(gbn);
            rb1 = *(const u16x8*)(gbn + 8);
        }
        bf16x8 afrag[4], bfrag[4];
#pragma unroll
        for (int m = 0; m < 4; ++m)
            afrag[m] = *(const bf16x8*)&alds[cur][(arow_base + m * 16) * LDT + ko];
#pragma unroll
        for (int n = 0; n < 4; ++n)
            bfrag[n] = *(const bf16x8*)&blds[cur][(brow_base + n * 16) * LDT + ko];
#pragma unroll
        for (int m = 0; m < 4; ++m)
#pragma unroll
            for (int n = 0; n < 4; ++n)
                acc[m][n] = __builtin_amdgcn_mfma_f32_16x16x32_bf16(afrag[m], bfrag[n],
                                                                   acc[m][n], 0, 0, 0);
        if (kt + 1 < nk) {
            *(u16x8*)&alds[cur ^ 1][wo] = ra0;  *(u16x8*)&alds[cur ^ 1][wo + 8] = ra1;
            *(u16x8*)&blds[cur ^ 1][wo] = rb0;  *(u16x8*)&blds[cur ^ 1][wo + 8] = rb1;
        }
        cur ^= 1;
    }

#pragma unroll
    for (int m = 0; m < 4; ++m)
#pragma unroll
        for (int n = 0; n < 4; ++n)
#pragma unroll
            for (int r = 0; r < 4; ++r) {
                int row = m0 + wm * 64 + m * 16 + (lane >> 4) * 4 + r;
                int col = n0 + wn * 64 + n * 16 + (lane & 15);
                size_t idx = (size_t)row * N + col;
                if (MODE == 0) Cb[idx] = f2bf(acc[m][n][r]);
                else           X[idx] = acc[m][n][r] + H[idx];
            }
}

// ---------------- V transpose ----------------
__global__ __launch_bounds__(256) void transpose_v_kernel(const u16* __restrict__ qkvb,
                                                          u16* __restrict__ vt) {
    __shared__ u16 tl[64][72];
    const int t = threadIdx.x;
    const int p = blockIdx.y;
    const int nn = p >> 1, b = p & 1;
    const int s0 = blockIdx.x * 64;
    const int r = t >> 2;
    const int ch = (t & 3) * 2;
    const u16* g = qkvb + ((size_t)(s0 + r) * 2 + b) * 3072 + 2048 + nn * 64;
    *(u16x8*)&tl[r][ch * 8]     = *(const u16x8*)(g + ch * 8);
    *(u16x8*)&tl[r][ch * 8 + 8] = *(const u16x8*)(g + ch * 8 + 8);
    __syncthreads();
    const int dh = t >> 2;
    const int sc = (t & 3) * 2;
    u16* o = vt + ((size_t)p * 64 + dh) * 2048 + s0;
#pragma unroll
    for (int q = 0; q < 2; ++q) {
        int scq = sc + q;
        u16x8 v;
#pragma unroll
        for (int j = 0; j < 8; ++j) v[j] = tl[scq * 8 + j][dh];
        *(u16x8*)(o + scq * 8) = v;
    }
}

// ---------------- causal flash attention (r5-proven structure) ----------------
// swapped QK^T (exp2 units), QBLK=64, permlane P-exchange, K/V LDS double-buffer
// with ONE barrier per tile-step, setprio around MFMA clusters.
__global__ __launch_bounds__(256) void attn_kernel(const u16* __restrict__ qkvb,
                                                   const u16* __restrict__ vt,
                                                   u16* __restrict__ attnb) {
    constexpr int LKT = 72;               // 64 + 8 pad
    __shared__ u16 klds[2][64 * LKT];
    __shared__ u16 vlds[2][64 * LKT];
#if !USE_PERMLANE
    __shared__ u16 plds[4][16 * LKT];
#endif
    const int t = threadIdx.x;
    const int lane = t & 63;
    const int w = t >> 6;
    const int bid = blockIdx.x;
    const int g = bid >> 5;               // 0..31
    const int sq = g & 7, jq = g >> 3;
    const int qt = (jq == 0) ? (31 - sq) : (jq == 1) ? (16 + sq)
                 : (jq == 2) ? (15 - sq) : sq;
    const int p = bid & 31;
    const int nn = p >> 1, b = p & 1;
    const int i0 = qt * 64;

    const int li = lane & 15;
    const int lg = lane >> 4;

    const int qrow = i0 + w * 16 + li;
    const u16* qg = qkvb + ((size_t)qrow * 2 + b) * 3072 + nn * 64 + lg * 8;
    bf16x8 qa0 = *(const bf16x8*)(qg);
    bf16x8 qa1 = *(const bf16x8*)(qg + 32);

    f32x4 o[4] = {};
    float mrun = -3.0e38f;
    float lrun = 0.f;

    const int srow = t >> 2;
    const int sch = (t & 3) * 2;
    const u16* kg = qkvb + 1024 + nn * 64 + sch * 8;
    const u16* vg = vt + ((size_t)p * 64 + srow) * 2048 + sch * 8;
    const int swo = srow * LKT + sch * 8;

    const int nt = qt + 1;
    u16x8 k0, k1, v0, v1;
    {
        const u16* kgp = kg + ((size_t)srow * 2 + b) * 3072;
        k0 = *(const u16x8*)(kgp);  k1 = *(const u16x8*)(kgp + 8);
        v0 = *(const u16x8*)(vg);   v1 = *(const u16x8*)(vg + 8);
    }
    *(u16x8*)&klds[0][swo] = k0;  *(u16x8*)&klds[0][swo + 8] = k1;
    *(u16x8*)&vlds[0][swo] = v0;  *(u16x8*)&vlds[0][swo + 8] = v1;
    __syncthreads();

    for (int jt = 0; jt < nt; ++jt) {
        const int buf = jt & 1;
        if (jt + 1 < nt) {
            const u16* kgp = kg + ((size_t)(jt * 64 + 64 + srow) * 2 + b) * 3072;
            k0 = *(const u16x8*)(kgp);  k1 = *(const u16x8*)(kgp + 8);
            const u16* vgp = vg + jt * 64 + 64;
            v0 = *(const u16x8*)(vgp);  v1 = *(const u16x8*)(vgp + 8);
        }

        f32x4 st[4];
        __builtin_amdgcn_s_setprio(1);
#pragma unroll
        for (int cf = 0; cf < 4; ++cf) {
            bf16x8 kb0 = *(const bf16x8*)&klds[buf][(cf * 16 + li) * LKT + lg * 8];
            bf16x8 kb1 = *(const bf16x8*)&klds[buf][(cf * 16 + li) * LKT + 32 + lg * 8];
            f32x4 z = {};
            z = __builtin_amdgcn_mfma_f32_16x16x32_bf16(kb0, qa0, z, 0, 0, 0);
            z = __builtin_amdgcn_mfma_f32_16x16x32_bf16(kb1, qa1, z, 0, 0, 0);
            st[cf] = z;
        }
        __builtin_amdgcn_s_setprio(0);

        if (jt == qt) {
            const int it = w * 16 + li;
#pragma unroll
            for (int cf = 0; cf < 4; ++cf)
#pragma unroll
                for (int r = 0; r < 4; ++r) {
                    int jl = cf * 16 + lg * 4 + r;
                    if (jl > it) st[cf][r] = -3.0e38f;
                }
        }

        float mloc = st[0][0];
#pragma unroll
        for (int cf = 0; cf < 4; ++cf)
#pragma unroll
            for (int r = 0; r < 4; ++r) mloc = fmaxf(mloc, st[cf][r]);
        mloc = fmaxf(mloc, __shfl_xor(mloc, 16, 64));
        mloc = fmaxf(mloc, __shfl_xor(mloc, 32, 64));

        if (__any(mloc > mrun + 8.0f)) {
            float mnew = fmaxf(mrun, mloc);
            float alpha = fexp2(mrun - mnew);
            lrun *= alpha;
            mrun = mnew;
#pragma unroll
            for (int r = 0; r < 4; ++r) {
                float ar = __shfl(alpha, lg * 4 + r, 64);
#pragma unroll
                for (int cf = 0; cf < 4; ++cf) o[cf][r] *= ar;
            }
        }

#if USE_PERMLANE
        float rsum = 0.f;
        u32 wv[4][2];
#pragma unroll
        for (int cf = 0; cf < 4; ++cf)
#pragma unroll
            for (int rr = 0; rr < 2; ++rr) {
                float p0 = fexp2(st[cf][2 * rr] - mrun);
                float p1 = fexp2(st[cf][2 * rr + 1] - mrun);
                rsum += p0 + p1;
                u32 wres;
                asm("v_cvt_pk_bf16_f32 %0, %1, %2" : "=v"(wres) : "v"(p0), "v"(p1));
                wv[cf][rr] = wres;
            }
        rsum += __shfl_xor(rsum, 16, 64);
        rsum += __shfl_xor(rsum, 32, 64);
        lrun += rsum;

        __builtin_amdgcn_s_setprio(1);
#pragma unroll
        for (int ks = 0; ks < 2; ++ks) {
            u32x2 sa = __builtin_amdgcn_permlane32_swap(wv[2 * ks][0], wv[2 * ks + 1][0], false, false);
            u32x2 fa = __builtin_amdgcn_permlane16_swap(sa[0], sa[1], false, false);
            u32x2 sb = __builtin_amdgcn_permlane32_swap(wv[2 * ks][1], wv[2 * ks + 1][1], false, false);
            u32x2 fb = __builtin_amdgcn_permlane16_swap(sb[0], sb[1], false, false);
            u32x4 fw = { fa[0], fb[0], fa[1], fb[1] };
            bf16x8 pa = __builtin_bit_cast(bf16x8, fw);
#pragma unroll
            for (int cf = 0; cf < 4; ++cf) {
                bf16x8 vb = *(const bf16x8*)&vlds[buf][(cf * 16 + li) * LKT + ks * 32 + lg * 8];
                o[cf] = __builtin_amdgcn_mfma_f32_16x16x32_bf16(pa, vb, o[cf], 0, 0, 0);
            }
        }
        __builtin_amdgcn_s_setprio(0);
#else
        float rsum = 0.f;
#pragma unroll
        for (int cf = 0; cf < 4; ++cf) {
            u16x4 pw;
#pragma unroll
            for (int r = 0; r < 4; ++r) {
                float pv = fexp2(st[cf][r] - mrun);
                rsum += pv;
                pw[r] = f2bf(pv);
            }
            *(u16x4*)&plds[w][li * LKT + cf * 16 + lg * 4] = pw;
        }
        rsum += __shfl_xor(rsum, 16, 64);
        rsum += __shfl_xor(rsum, 32, 64);
        lrun += rsum;

        asm volatile("s_waitcnt lgkmcnt(0)" ::: "memory");
        __builtin_amdgcn_sched_barrier(0);

#pragma unroll
        for (int ks = 0; ks < 2; ++ks) {
            bf16x8 pa = *(const bf16x8*)&plds[w][li * LKT + ks * 32 + lg * 8];
#pragma unroll
            for (int cf = 0; cf < 4; ++cf) {
                bf16x8 vb = *(const bf16x8*)&vlds[buf][(cf * 16 + li) * LKT + ks * 32 + lg * 8];
                o[cf] = __builtin_amdgcn_mfma_f32_16x16x32_bf16(pa, vb, o[cf], 0, 0, 0);
            }
        }
#endif

        if (jt + 1 < nt) {
            *(u16x8*)&klds[buf ^ 1][swo] = k0;  *(u16x8*)&klds[buf ^ 1][swo + 8] = k1;
            *(u16x8*)&vlds[buf ^ 1][swo] = v0;  *(u16x8*)&vlds[buf ^ 1][swo + 8] = v1;
        }
        __syncthreads();
    }

    float rinv = frcp(lrun);
#pragma unroll
    for (int r = 0; r < 4; ++r) {
        float rv = __shfl(rinv, lg * 4 + r, 64);
        int srowg = i0 + w * 16 + lg * 4 + r;
        u16* og = attnb + ((size_t)srowg * 2 + b) * 1024 + nn * 64;
#pragma unroll
        for (int cf = 0; cf < 4; ++cf)
            og[cf * 16 + li] = f2bf(o[cf][r] * rv);
    }
}

// ---------------- residual LayerNorm ----------------
__global__ __launch_bounds__(256) void ln_kernel(const float* __restrict__ X,
                                                 const float* __restrict__ gamma,
                                                 const float* __restrict__ beta,
                                                 float* __restrict__ out) {
    __shared__ float red[8];
    const int t = threadIdx.x;
    const int row = blockIdx.x;
    float4 v = ((const float4*)(X + (size_t)row * 1024))[t];
    float s = v.x + v.y + v.z + v.w;
#pragma unroll
    for (int off = 1; off < 64; off <<= 1) s += __shfl_xor(s, off, 64);
    if ((t & 63) == 0) red[t >> 6] = s;
    __syncthreads();
    float mu = (red[0] + red[1] + red[2] + red[3]) * (1.f / 1024.f);
    float dx = v.x - mu, dy = v.y - mu, dz = v.z - mu, dw = v.w - mu;
    float q = dx * dx + dy * dy + dz * dz + dw * dw;
#pragma unroll
    for (int off = 1; off < 64; off <<= 1) q += __shfl_xor(q, off, 64);
    if ((t & 63) == 0) red[4 + (t >> 6)] = q;
    __syncthreads();
    float var = (red[4] + red[5] + red[6] + red[7]) * (1.f / 1024.f);
    float rs = rsqrtf(var + 1e-5f);
    float4 g = ((const float4*)gamma)[t];
    float4 bt = ((const float4*)beta)[t];
    float4 o;
    o.x = dx * rs * g.x + bt.x;
    o.y = dy * rs * g.y + bt.y;
    o.z = dz * rs * g.z + bt.z;
    o.w = dw * rs * g.w + bt.w;
    ((float4*)(out + (size_t)row * 1024))[t] = o;
}

// ---------------- launch ----------------
extern "C" void kernel_launch(void* const* d_in, const int* in_sizes, int n_in,
                              void* d_out, int out_size, void* d_ws, size_t ws_size,
                              hipStream_t stream) {
    const float* h     = (const float*)d_in[0];
    // d_in[1] = attn_mask (deterministic causal triu; applied analytically)
    const float* Wqkv  = (const float*)d_in[2];
    const float* Wo    = (const float*)d_in[3];
    const float* gamma = (const float*)d_in[4];
    const float* beta  = (const float*)d_in[5];
    float* out = (float*)d_out;

    char* ws = (char*)d_ws;
    u16*   hb    = (u16*)(ws);
    u16*   wqkvt = (u16*)(ws + 8388608);
    u16*   wot   = (u16*)(ws + 14680064);
    u16*   qkvb  = (u16*)(ws + 16777216);
    u16*   vt    = (u16*)(ws + 41943040);
    u16*   attnb = (u16*)(ws + 50331648);
    float* xbuf  = (float*)(ws + 58720256);

    const float qscale = 0.125f * 1.44269504088896f;  // 1/sqrt(Dh) * log2(e)

    conv_h_kernel<<<4096, 256, 0, stream>>>(h, hb);
    conv_wt_kernel<<<dim3(96, 32), 256, 0, stream>>>(Wqkv, wqkvt, 1024, 3072, 1024, qscale);
    conv_wt_kernel<<<dim3(32, 32), 256, 0, stream>>>(Wo, wot, 1024, 1024, 0, 1.0f);
    gemm1_8ph_kernel<<<192, 512, 0, stream>>>(hb, wqkvt, qkvb, 4096, 3072, 1024);
    transpose_v_kernel<<<dim3(32, 32), 256, 0, stream>>>(qkvb, vt);
    attn_kernel<<<1024, 256, 0, stream>>>(qkvb, vt, attnb);
    gemm_bt_kernel<1><<<dim3(32, 8), 256, 0, stream>>>(attnb, wot, nullptr, h, xbuf,
                                                       4096, 1024, 1024);
    ln_kernel<<<4096, 256, 0, stream>>>(xbuf, gamma, beta, out);
}

// Round 13
// 123.334 us; speedup vs baseline: 1.0961x; 1.0107x over previous
//
#include <hip/hip_runtime.h>

typedef unsigned short u16;
typedef unsigned int u32;
typedef __attribute__((ext_vector_type(8))) __bf16 bf16x8;
typedef __attribute__((ext_vector_type(4))) float f32x4;
typedef __attribute__((ext_vector_type(8))) unsigned short u16x8;
typedef __attribute__((ext_vector_type(4))) unsigned short u16x4;
typedef __attribute__((ext_vector_type(2))) unsigned int u32x2;
typedef __attribute__((ext_vector_type(4))) unsigned int u32x4;

#if defined(__has_builtin)
#if __has_builtin(__builtin_amdgcn_permlane32_swap) && __has_builtin(__builtin_amdgcn_permlane16_swap)
#define USE_PERMLANE 1
#endif
#endif
#ifndef USE_PERMLANE
#define USE_PERMLANE 0
#endif

__device__ __forceinline__ u16 f2bf(float f) {
    u32 u = __builtin_bit_cast(u32, f);
    u += 0x7fffu + ((u >> 16) & 1u);   // round-to-nearest-even
    return (u16)(u >> 16);
}

__device__ __forceinline__ float fexp2(float x) {
#if __has_builtin(__builtin_amdgcn_exp2f)
    return __builtin_amdgcn_exp2f(x);
#else
    return exp2f(x);
#endif
}

__device__ __forceinline__ float frcp(float x) {
#if __has_builtin(__builtin_amdgcn_rcpf)
    return __builtin_amdgcn_rcpf(x);
#else
    return 1.0f / x;
#endif
}

__device__ __forceinline__ u16x8 cvt8(float4 a, float4 b) {
    u16x8 o = { f2bf(a.x), f2bf(a.y), f2bf(a.z), f2bf(a.w),
                f2bf(b.x), f2bf(b.y), f2bf(b.z), f2bf(b.w) };
    return o;
}

// W [R][C] f32 -> Wt [C][R] bf16 (transpose + convert); rows < scale_rows get *scale
__global__ __launch_bounds__(256) void conv_wt_kernel(const float* __restrict__ W,
                                                      u16* __restrict__ Wt,
                                                      int R, int C,
                                                      int scale_rows, float scale) {
    __shared__ float tile[32][33];
    int t = threadIdx.x;
    int r = t >> 3, c4 = (t & 7) * 4;
    int gx = blockIdx.x * 32, gy = blockIdx.y * 32;
    float4 v = *(const float4*)&W[(size_t)(gy + r) * C + gx + c4];
    tile[r][c4 + 0] = v.x; tile[r][c4 + 1] = v.y;
    tile[r][c4 + 2] = v.z; tile[r][c4 + 3] = v.w;
    __syncthreads();
    float sc = (gx + r < scale_rows) ? scale : 1.0f;
    u16x4 o = { f2bf(tile[c4 + 0][r] * sc), f2bf(tile[c4 + 1][r] * sc),
                f2bf(tile[c4 + 2][r] * sc), f2bf(tile[c4 + 3][r] * sc) };
    *(u16x4*)&Wt[(size_t)(gx + r) * R + gy + c4] = o;
}

// ---------------- gemm1: qkv = h(f32, converted in-staging) x Wqkv^T ----------------
// reg-staged 2-phase, padded LDS (r5-proven structure); A read as f32 and
// converted to bf16 in registers during staging (conv_h pass fused away).
__global__ __launch_bounds__(256) void gemm_h_kernel(
        const float* __restrict__ Af, const u16* __restrict__ Bt,
        u16* __restrict__ Cb, int M, int N, int K) {
    constexpr int LDT = 40;                 // 32 + 8 pad
    __shared__ u16 alds[2][128 * LDT];
    __shared__ u16 blds[2][128 * LDT];
    const int t = threadIdx.x;
    const int lane = t & 63;
    const int wave = t >> 6;
    const int wm = wave >> 1, wn = wave & 1;
    const int m0 = blockIdx.x * 128;
    const int n0 = blockIdx.y * 128;
    const int nk = K >> 5;

    const int srow = t >> 1;
    const int sch = (t & 1) * 2;
    const float* ga = Af + (size_t)(m0 + srow) * K + sch * 8;
    const u16* gb = Bt + (size_t)(n0 + srow) * K + sch * 8;
    const int wo = srow * LDT + sch * 8;

    float4 fa0 = *(const float4*)(ga);
    float4 fa1 = *(const float4*)(ga + 4);
    float4 fa2 = *(const float4*)(ga + 8);
    float4 fa3 = *(const float4*)(ga + 12);
    u16x8 rb0 = *(const u16x8*)(gb);
    u16x8 rb1 = *(const u16x8*)(gb + 8);
    *(u16x8*)&alds[0][wo] = cvt8(fa0, fa1);
    *(u16x8*)&alds[0][wo + 8] = cvt8(fa2, fa3);
    *(u16x8*)&blds[0][wo] = rb0;  *(u16x8*)&blds[0][wo + 8] = rb1;

    f32x4 acc[4][4] = {};
    const int ko = (lane >> 4) * 8;
    const int arow_base = wm * 64 + (lane & 15);
    const int brow_base = wn * 64 + (lane & 15);

    int cur = 0;
    for (int kt = 0; kt < nk; ++kt) {
        __syncthreads();
        if (kt + 1 < nk) {
            const float* gan = ga + (kt + 1) * 32;
            const u16* gbn = gb + (kt + 1) * 32;
            fa0 = *(const float4*)(gan);
            fa1 = *(const float4*)(gan + 4);
            fa2 = *(const float4*)(gan + 8);
            fa3 = *(const float4*)(gan + 12);
            rb0 = *(const u16x8*)(gbn);
            rb1 = *(const u16x8*)(gbn + 8);
        }
        bf16x8 afrag[4], bfrag[4];
#pragma unroll
        for (int m = 0; m < 4; ++m)
            afrag[m] = *(const bf16x8*)&alds[cur][(arow_base + m * 16) * LDT + ko];
#pragma unroll
        for (int n = 0; n < 4; ++n)
            bfrag[n] = *(const bf16x8*)&blds[cur][(brow_base + n * 16) * LDT + ko];
#pragma unroll
        for (int m = 0; m < 4; ++m)
#pragma unroll
            for (int n = 0; n < 4; ++n)
                acc[m][n] = __builtin_amdgcn_mfma_f32_16x16x32_bf16(afrag[m], bfrag[n],
                                                                   acc[m][n], 0, 0, 0);
        if (kt + 1 < nk) {
            *(u16x8*)&alds[cur ^ 1][wo] = cvt8(fa0, fa1);
            *(u16x8*)&alds[cur ^ 1][wo + 8] = cvt8(fa2, fa3);
            *(u16x8*)&blds[cur ^ 1][wo] = rb0;  *(u16x8*)&blds[cur ^ 1][wo + 8] = rb1;
        }
        cur ^= 1;
    }

#pragma unroll
    for (int m = 0; m < 4; ++m)
#pragma unroll
        for (int n = 0; n < 4; ++n)
#pragma unroll
            for (int r = 0; r < 4; ++r) {
                int row = m0 + wm * 64 + m * 16 + (lane >> 4) * 4 + r;
                int col = n0 + wn * 64 + n * 16 + (lane & 15);
                Cb[(size_t)row * N + col] = f2bf(acc[m][n][r]);
            }
}

// ---------------- gemm2: X = attn_vec x Wo^T + h (f32 out) ----------------
__global__ __launch_bounds__(256) void gemm_bt_kernel(
        const u16* __restrict__ A, const u16* __restrict__ Bt,
        const float* __restrict__ H, float* __restrict__ X,
        int M, int N, int K) {
    constexpr int LDT = 40;                 // 32 + 8 pad
    __shared__ u16 alds[2][128 * LDT];
    __shared__ u16 blds[2][128 * LDT];
    const int t = threadIdx.x;
    const int lane = t & 63;
    const int wave = t >> 6;
    const int wm = wave >> 1, wn = wave & 1;
    const int m0 = blockIdx.x * 128;
    const int n0 = blockIdx.y * 128;
    const int nk = K >> 5;

    const int srow = t >> 1;
    const int sch = (t & 1) * 2;
    const u16* ga = A + (size_t)(m0 + srow) * K + sch * 8;
    const u16* gb = Bt + (size_t)(n0 + srow) * K + sch * 8;
    const int wo = srow * LDT + sch * 8;

    u16x8 ra0 = *(const u16x8*)(ga);
    u16x8 ra1 = *(const u16x8*)(ga + 8);
    u16x8 rb0 = *(const u16x8*)(gb);
    u16x8 rb1 = *(const u16x8*)(gb + 8);
    *(u16x8*)&alds[0][wo] = ra0;  *(u16x8*)&alds[0][wo + 8] = ra1;
    *(u16x8*)&blds[0][wo] = rb0;  *(u16x8*)&blds[0][wo + 8] = rb1;

    f32x4 acc[4][4] = {};
    const int ko = (lane >> 4) * 8;
    const int arow_base = wm * 64 + (lane & 15);
    const int brow_base = wn * 64 + (lane & 15);

    int cur = 0;
    for (int kt = 0; kt < nk; ++kt) {
        __syncthreads();
        if (kt + 1 < nk) {
            const u16* gan = ga + (kt + 1) * 32;
            const u16* gbn = gb + (kt + 1) * 32;
            ra0 = *(const u16x8*)(gan);
            ra1 = *(const u16x8*)(gan + 8);
            rb0 = *(const u16x8*)(gbn);
            rb1 = *(const u16x8*)(gbn + 8);
        }
        bf16x8 afrag[4], bfrag[4];
#pragma unroll
        for (int m = 0; m < 4; ++m)
            afrag[m] = *(const bf16x8*)&alds[cur][(arow_base + m * 16) * LDT + ko];
#pragma unroll
        for (int n = 0; n < 4; ++n)
            bfrag[n] = *(const bf16x8*)&blds[cur][(brow_base + n * 16) * LDT + ko];
#pragma unroll
        for (int m = 0; m < 4; ++m)
#pragma unroll
            for (int n = 0; n < 4; ++n)
                acc[m][n] = __builtin_amdgcn_mfma_f32_16x16x32_bf16(afrag[m], bfrag[n],
                                                                   acc[m][n], 0, 0, 0);
        if (kt + 1 < nk) {
            *(u16x8*)&alds[cur ^ 1][wo] = ra0;  *(u16x8*)&alds[cur ^ 1][wo + 8] = ra1;
            *(u16x8*)&blds[cur ^ 1][wo] = rb0;  *(u16x8*)&blds[cur ^ 1][wo + 8] = rb1;
        }
        cur ^= 1;
    }

#pragma unroll
    for (int m = 0; m < 4; ++m)
#pragma unroll
        for (int n = 0; n < 4; ++n)
#pragma unroll
            for (int r = 0; r < 4; ++r) {
                int row = m0 + wm * 64 + m * 16 + (lane >> 4) * 4 + r;
                int col = n0 + wn * 64 + n * 16 + (lane & 15);
                size_t idx = (size_t)row * N + col;
                X[idx] = acc[m][n][r] + H[idx];
            }
}

// ---------------- V transpose ----------------
__global__ __launch_bounds__(256) void transpose_v_kernel(const u16* __restrict__ qkvb,
                                                          u16* __restrict__ vt) {
    __shared__ u16 tl[64][72];
    const int t = threadIdx.x;
    const int p = blockIdx.y;
    const int nn = p >> 1, b = p & 1;
    const int s0 = blockIdx.x * 64;
    const int r = t >> 2;
    const int ch = (t & 3) * 2;
    const u16* g = qkvb + ((size_t)(s0 + r) * 2 + b) * 3072 + 2048 + nn * 64;
    *(u16x8*)&tl[r][ch * 8]     = *(const u16x8*)(g + ch * 8);
    *(u16x8*)&tl[r][ch * 8 + 8] = *(const u16x8*)(g + ch * 8 + 8);
    __syncthreads();
    const int dh = t >> 2;
    const int sc = (t & 3) * 2;
    u16* o = vt + ((size_t)p * 64 + dh) * 2048 + s0;
#pragma unroll
    for (int q = 0; q < 2; ++q) {
        int scq = sc + q;
        u16x8 v;
#pragma unroll
        for (int j = 0; j < 8; ++j) v[j] = tl[scq * 8 + j][dh];
        *(u16x8*)(o + scq * 8) = v;
    }
}

// ---------------- causal flash attention (r5-proven structure) ----------------
__global__ __launch_bounds__(256) void attn_kernel(const u16* __restrict__ qkvb,
                                                   const u16* __restrict__ vt,
                                                   u16* __restrict__ attnb) {
    constexpr int LKT = 72;               // 64 + 8 pad
    __shared__ u16 klds[2][64 * LKT];
    __shared__ u16 vlds[2][64 * LKT];
#if !USE_PERMLANE
    __shared__ u16 plds[4][16 * LKT];
#endif
    const int t = threadIdx.x;
    const int lane = t & 63;
    const int w = t >> 6;
    const int bid = blockIdx.x;
    const int g = bid >> 5;               // 0..31
    const int sq = g & 7, jq = g >> 3;
    const int qt = (jq == 0) ? (31 - sq) : (jq == 1) ? (16 + sq)
                 : (jq == 2) ? (15 - sq) : sq;
    const int p = bid & 31;
    const int nn = p >> 1, b = p & 1;
    const int i0 = qt * 64;

    const int li = lane & 15;
    const int lg = lane >> 4;

    const int qrow = i0 + w * 16 + li;
    const u16* qg = qkvb + ((size_t)qrow * 2 + b) * 3072 + nn * 64 + lg * 8;
    bf16x8 qa0 = *(const bf16x8*)(qg);
    bf16x8 qa1 = *(const bf16x8*)(qg + 32);

    f32x4 o[4] = {};
    float mrun = -3.0e38f;
    float lrun = 0.f;

    const int srow = t >> 2;
    const int sch = (t & 3) * 2;
    const u16* kg = qkvb + 1024 + nn * 64 + sch * 8;
    const u16* vg = vt + ((size_t)p * 64 + srow) * 2048 + sch * 8;
    const int swo = srow * LKT + sch * 8;

    const int nt = qt + 1;
    u16x8 k0, k1, v0, v1;
    {
        const u16* kgp = kg + ((size_t)srow * 2 + b) * 3072;
        k0 = *(const u16x8*)(kgp);  k1 = *(const u16x8*)(kgp + 8);
        v0 = *(const u16x8*)(vg);   v1 = *(const u16x8*)(vg + 8);
    }
    *(u16x8*)&klds[0][swo] = k0;  *(u16x8*)&klds[0][swo + 8] = k1;
    *(u16x8*)&vlds[0][swo] = v0;  *(u16x8*)&vlds[0][swo + 8] = v1;
    __syncthreads();

    for (int jt = 0; jt < nt; ++jt) {
        const int buf = jt & 1;
        if (jt + 1 < nt) {
            const u16* kgp = kg + ((size_t)(jt * 64 + 64 + srow) * 2 + b) * 3072;
            k0 = *(const u16x8*)(kgp);  k1 = *(const u16x8*)(kgp + 8);
            const u16* vgp = vg + jt * 64 + 64;
            v0 = *(const u16x8*)(vgp);  v1 = *(const u16x8*)(vgp + 8);
        }

        f32x4 st[4];
        __builtin_amdgcn_s_setprio(1);
#pragma unroll
        for (int cf = 0; cf < 4; ++cf) {
            bf16x8 kb0 = *(const bf16x8*)&klds[buf][(cf * 16 + li) * LKT + lg * 8];
            bf16x8 kb1 = *(const bf16x8*)&klds[buf][(cf * 16 + li) * LKT + 32 + lg * 8];
            f32x4 z = {};
            z = __builtin_amdgcn_mfma_f32_16x16x32_bf16(kb0, qa0, z, 0, 0, 0);
            z = __builtin_amdgcn_mfma_f32_16x16x32_bf16(kb1, qa1, z, 0, 0, 0);
            st[cf] = z;
        }
        __builtin_amdgcn_s_setprio(0);

        if (jt == qt) {
            const int it = w * 16 + li;
#pragma unroll
            for (int cf = 0; cf < 4; ++cf)
#pragma unroll
                for (int r = 0; r < 4; ++r) {
                    int jl = cf * 16 + lg * 4 + r;
                    if (jl > it) st[cf][r] = -3.0e38f;
                }
        }

        float mloc = st[0][0];
#pragma unroll
        for (int cf = 0; cf < 4; ++cf)
#pragma unroll
            for (int r = 0; r < 4; ++r) mloc = fmaxf(mloc, st[cf][r]);
        mloc = fmaxf(mloc, __shfl_xor(mloc, 16, 64));
        mloc = fmaxf(mloc, __shfl_xor(mloc, 32, 64));

        if (__any(mloc > mrun + 8.0f)) {
            float mnew = fmaxf(mrun, mloc);
            float alpha = fexp2(mrun - mnew);
            lrun *= alpha;
            mrun = mnew;
#pragma unroll
            for (int r = 0; r < 4; ++r) {
                float ar = __shfl(alpha, lg * 4 + r, 64);
#pragma unroll
                for (int cf = 0; cf < 4; ++cf) o[cf][r] *= ar;
            }
        }

#if USE_PERMLANE
        float rsum = 0.f;
        u32 wv[4][2];
#pragma unroll
        for (int cf = 0; cf < 4; ++cf)
#pragma unroll
            for (int rr = 0; rr < 2; ++rr) {
                float p0 = fexp2(st[cf][2 * rr] - mrun);
                float p1 = fexp2(st[cf][2 * rr + 1] - mrun);
                rsum += p0 + p1;
                u32 wres;
                asm("v_cvt_pk_bf16_f32 %0, %1, %2" : "=v"(wres) : "v"(p0), "v"(p1));
                wv[cf][rr] = wres;
            }
        rsum += __shfl_xor(rsum, 16, 64);
        rsum += __shfl_xor(rsum, 32, 64);
        lrun += rsum;

        __builtin_amdgcn_s_setprio(1);
#pragma unroll
        for (int ks = 0; ks < 2; ++ks) {
            u32x2 sa = __builtin_amdgcn_permlane32_swap(wv[2 * ks][0], wv[2 * ks + 1][0], false, false);
            u32x2 fa = __builtin_amdgcn_permlane16_swap(sa[0], sa[1], false, false);
            u32x2 sb = __builtin_amdgcn_permlane32_swap(wv[2 * ks][1], wv[2 * ks + 1][1], false, false);
            u32x2 fb = __builtin_amdgcn_permlane16_swap(sb[0], sb[1], false, false);
            u32x4 fw = { fa[0], fb[0], fa[1], fb[1] };
            bf16x8 pa = __builtin_bit_cast(bf16x8, fw);
#pragma unroll
            for (int cf = 0; cf < 4; ++cf) {
                bf16x8 vb = *(const bf16x8*)&vlds[buf][(cf * 16 + li) * LKT + ks * 32 + lg * 8];
                o[cf] = __builtin_amdgcn_mfma_f32_16x16x32_bf16(pa, vb, o[cf], 0, 0, 0);
            }
        }
        __builtin_amdgcn_s_setprio(0);
#else
        float rsum = 0.f;
#pragma unroll
        for (int cf = 0; cf < 4; ++cf) {
            u16x4 pw;
#pragma unroll
            for (int r = 0; r < 4; ++r) {
                float pv = fexp2(st[cf][r] - mrun);
                rsum += pv;
                pw[r] = f2bf(pv);
            }
            *(u16x4*)&plds[w][li * LKT + cf * 16 + lg * 4] = pw;
        }
        rsum += __shfl_xor(rsum, 16, 64);
        rsum += __shfl_xor(rsum, 32, 64);
        lrun += rsum;

        asm volatile("s_waitcnt lgkmcnt(0)" ::: "memory");
        __builtin_amdgcn_sched_barrier(0);

#pragma unroll
        for (int ks = 0; ks < 2; ++ks) {
            bf16x8 pa = *(const bf16x8*)&plds[w][li * LKT + ks * 32 + lg * 8];
#pragma unroll
            for (int cf = 0; cf < 4; ++cf) {
                bf16x8 vb = *(const bf16x8*)&vlds[buf][(cf * 16 + li) * LKT + ks * 32 + lg * 8];
                o[cf] = __builtin_amdgcn_mfma_f32_16x16x32_bf16(pa, vb, o[cf], 0, 0, 0);
            }
        }
#endif

        if (jt + 1 < nt) {
            *(u16x8*)&klds[buf ^ 1][swo] = k0;  *(u16x8*)&klds[buf ^ 1][swo + 8] = k1;
            *(u16x8*)&vlds[buf ^ 1][swo] = v0;  *(u16x8*)&vlds[buf ^ 1][swo + 8] = v1;
        }
        __syncthreads();
    }

    float rinv = frcp(lrun);
#pragma unroll
    for (int r = 0; r < 4; ++r) {
        float rv = __shfl(rinv, lg * 4 + r, 64);
        int srowg = i0 + w * 16 + lg * 4 + r;
        u16* og = attnb + ((size_t)srowg * 2 + b) * 1024 + nn * 64;
#pragma unroll
        for (int cf = 0; cf < 4; ++cf)
            og[cf * 16 + li] = f2bf(o[cf][r] * rv);
    }
}

// ---------------- residual LayerNorm ----------------
__global__ __launch_bounds__(256) void ln_kernel(const float* __restrict__ X,
                                                 const float* __restrict__ gamma,
                                                 const float* __restrict__ beta,
                                                 float* __restrict__ out) {
    __shared__ float red[8];
    const int t = threadIdx.x;
    const int row = blockIdx.x;
    float4 v = ((const float4*)(X + (size_t)row * 1024))[t];
    float s = v.x + v.y + v.z + v.w;
#pragma unroll
    for (int off = 1; off < 64; off <<= 1) s += __shfl_xor(s, off, 64);
    if ((t & 63) == 0) red[t >> 6] = s;
    __syncthreads();
    float mu = (red[0] + red[1] + red[2] + red[3]) * (1.f / 1024.f);
    float dx = v.x - mu, dy = v.y - mu, dz = v.z - mu, dw = v.w - mu;
    float q = dx * dx + dy * dy + dz * dz + dw * dw;
#pragma unroll
    for (int off = 1; off < 64; off <<= 1) q += __shfl_xor(q, off, 64);
    if ((t & 63) == 0) red[4 + (t >> 6)] = q;
    __syncthreads();
    float var = (red[4] + red[5] + red[6] + red[7]) * (1.f / 1024.f);
    float rs = rsqrtf(var + 1e-5f);
    float4 g = ((const float4*)gamma)[t];
    float4 bt = ((const float4*)beta)[t];
    float4 o;
    o.x = dx * rs * g.x + bt.x;
    o.y = dy * rs * g.y + bt.y;
    o.z = dz * rs * g.z + bt.z;
    o.w = dw * rs * g.w + bt.w;
    ((float4*)(out + (size_t)row * 1024))[t] = o;
}

// ---------------- launch ----------------
extern "C" void kernel_launch(void* const* d_in, const int* in_sizes, int n_in,
                              void* d_out, int out_size, void* d_ws, size_t ws_size,
                              hipStream_t stream) {
    const float* h     = (const float*)d_in[0];
    // d_in[1] = attn_mask (deterministic causal triu; applied analytically)
    const float* Wqkv  = (const float*)d_in[2];
    const float* Wo    = (const float*)d_in[3];
    const float* gamma = (const float*)d_in[4];
    const float* beta  = (const float*)d_in[5];
    float* out = (float*)d_out;

    char* ws = (char*)d_ws;
    u16*   wqkvt = (u16*)(ws + 8388608);
    u16*   wot   = (u16*)(ws + 14680064);
    u16*   qkvb  = (u16*)(ws + 16777216);
    u16*   vt    = (u16*)(ws + 41943040);
    u16*   attnb = (u16*)(ws + 50331648);
    float* xbuf  = (float*)(ws + 58720256);

    const float qscale = 0.125f * 1.44269504088896f;  // 1/sqrt(Dh) * log2(e)

    conv_wt_kernel<<<dim3(96, 32), 256, 0, stream>>>(Wqkv, wqkvt, 1024, 3072, 1024, qscale);
    conv_wt_kernel<<<dim3(32, 32), 256, 0, stream>>>(Wo, wot, 1024, 1024, 0, 1.0f);
    gemm_h_kernel<<<dim3(32, 24), 256, 0, stream>>>(h, wqkvt, qkvb, 4096, 3072, 1024);
    transpose_v_kernel<<<dim3(32, 32), 256, 0, stream>>>(qkvb, vt);
    attn_kernel<<<1024, 256, 0, stream>>>(qkvb, vt, attnb);
    gemm_bt_kernel<<<dim3(32, 8), 256, 0, stream>>>(attnb, wot, h, xbuf, 4096, 1024, 1024);
    ln_kernel<<<4096, 256, 0, stream>>>(xbuf, gamma, beta, out);
}

// Round 14
// 122.729 us; speedup vs baseline: 1.1015x; 1.0049x over previous
//
#include <hip/hip_runtime.h>

typedef unsigned short u16;
typedef unsigned int u32;
typedef __attribute__((ext_vector_type(8))) __bf16 bf16x8;
typedef __attribute__((ext_vector_type(4))) float f32x4;
typedef __attribute__((ext_vector_type(8))) unsigned short u16x8;
typedef __attribute__((ext_vector_type(4))) unsigned short u16x4;
typedef __attribute__((ext_vector_type(2))) unsigned int u32x2;
typedef __attribute__((ext_vector_type(4))) unsigned int u32x4;

#if defined(__has_builtin)
#if __has_builtin(__builtin_amdgcn_permlane32_swap) && __has_builtin(__builtin_amdgcn_permlane16_swap)
#define USE_PERMLANE 1
#endif
#endif
#ifndef USE_PERMLANE
#define USE_PERMLANE 0
#endif

__device__ __forceinline__ u16 f2bf(float f) {
    u32 u = __builtin_bit_cast(u32, f);
    u += 0x7fffu + ((u >> 16) & 1u);   // round-to-nearest-even
    return (u16)(u >> 16);
}

__device__ __forceinline__ float fexp2(float x) {
#if __has_builtin(__builtin_amdgcn_exp2f)
    return __builtin_amdgcn_exp2f(x);
#else
    return exp2f(x);
#endif
}

__device__ __forceinline__ float frcp(float x) {
#if __has_builtin(__builtin_amdgcn_rcpf)
    return __builtin_amdgcn_rcpf(x);
#else
    return 1.0f / x;
#endif
}

#define GL16(gp, lp) __builtin_amdgcn_global_load_lds(                           \
    (const __attribute__((address_space(1))) void*)(gp),                          \
    (__attribute__((address_space(3))) void*)(lp), 16, 0, 0)

// ---------------- conversions ----------------
__global__ __launch_bounds__(256) void conv_h_kernel(const float* __restrict__ h,
                                                     u16* __restrict__ hb) {
    int i = blockIdx.x * 256 + threadIdx.x;
    float4 v = ((const float4*)h)[i];
    u16x4 o = { f2bf(v.x), f2bf(v.y), f2bf(v.z), f2bf(v.w) };
    ((u16x4*)hb)[i] = o;
}

// W [R][C] f32 -> Wt [C][R] bf16 (transpose + convert); rows < scale_rows get *scale
__global__ __launch_bounds__(256) void conv_wt_kernel(const float* __restrict__ W,
                                                      u16* __restrict__ Wt,
                                                      int R, int C,
                                                      int scale_rows, float scale) {
    __shared__ float tile[32][33];
    int t = threadIdx.x;
    int r = t >> 3, c4 = (t & 7) * 4;
    int gx = blockIdx.x * 32, gy = blockIdx.y * 32;
    float4 v = *(const float4*)&W[(size_t)(gy + r) * C + gx + c4];
    tile[r][c4 + 0] = v.x; tile[r][c4 + 1] = v.y;
    tile[r][c4 + 2] = v.z; tile[r][c4 + 3] = v.w;
    __syncthreads();
    float sc = (gx + r < scale_rows) ? scale : 1.0f;
    u16x4 o = { f2bf(tile[c4 + 0][r] * sc), f2bf(tile[c4 + 1][r] * sc),
                f2bf(tile[c4 + 2][r] * sc), f2bf(tile[c4 + 3][r] * sc) };
    *(u16x4*)&Wt[(size_t)(gx + r) * R + gy + c4] = o;
}

// ============ gemm1: 8-phase 256x256xBK64, counted vmcnt(8), gload_lds ============
// Fixes vs r12: (1) vmcnt(8) at P2/P4/P6/P8 — every wait targets loads issued >=4
// phases earlier, 8 loads always in flight (r12's vmcnt(4) over-drained, exposing
// HBM latency); (2) swizzle f(row)=(row>>1)&3 -> exact 2-way bank alias (free);
// (3) 4m x 6n tile group per XCD (5MB L2 working set).
// Steady-state ledger (Lp = 2 loads issued at phase p):
//   enter iter: outstanding = prev{L5..L8} (8)
//   P1 rd buf0.ks0 (prevL3,L4: retired prev-P8)   issue L1 = B1.A.ks1(t1)
//   P2 rd buf0.ks0'                               issue L2 = B1.B.ks1; W8 -> ret prevL5,L6
//   P3 rd buf0.ks1 (prevL5,L6 ok)                 issue L3 = B0.A.ks0(t2)
//   P4 rd buf0.ks1'                               issue L4 = B0.B.ks0; W8 -> ret prevL7,L8
//   P5 rd buf1.ks0 (prevL7,L8 ok)                 issue L5 = B0.A.ks1(t2)
//   P6 rd buf1.ks0'                               issue L6 = B0.B.ks1; W8 -> ret L1,L2
//   P7 rd buf1.ks1 (L1,L2 ok)                     issue L7 = B1.A.ks0(t3)
//   P8 rd buf1.ks1'                               issue L8 = B1.B.ks0; W8 -> ret L3,L4
//   exit: outstanding = {L5..L8} (8)  [invariant holds]
__global__ __launch_bounds__(512, 2) void gemm1_8ph_kernel(
        const u16* __restrict__ A, const u16* __restrict__ Bt,
        u16* __restrict__ Cb, int M, int N, int K) {
    __shared__ u16 alds[2][2][8192];   // [buf][ks][row*32 + col]
    __shared__ u16 blds[2][2][8192];
    const int t = threadIdx.x;
    const int lane = t & 63;
    const int wave = t >> 6;           // 0..7
    const int wm = wave >> 2;          // 0..1
    const int wn = wave & 3;           // 0..3
    const int li = lane & 15, lg = lane >> 4;

    // XCD map: xcd = lin%8 covers a 4m x 6n tile group (A 2MB + B 3MB = 5MB/L2)
    const int lin = (int)blockIdx.x;   // 0..191
    const int xcd = lin & 7;
    const int c = lin >> 3;            // 0..23
    const int mi = c & 3, ni = c >> 2; // 4 x 6
    const int m0 = ((xcd & 3) * 4 + mi) << 8;
    const int n0 = (((xcd >> 2) * 6) + ni) << 8;

    // staging: wave covers rows [wave*32, wave*32+32) of each 16KB half (2 instrs).
    // lane l -> row (l>>2); source slot = stored(l&3) ^ f(row), f(row)=(row>>1)&3
    // = ((l>>3)&3)  [row = 16q + (l>>2), 16q contributes 0 mod 4 after >>1]
    const int srow = lane >> 2;
    const int sslot = ((lane & 3) ^ ((lane >> 3) & 3)) * 8;   // u16 units
    const u16* gAb = A + (size_t)(m0 + wave * 32 + srow) * K + sslot;
    const u16* gBb = Bt + (size_t)(n0 + wave * 32 + srow) * K + sslot;
    const int ldst = wave * 1024;      // u16 offset; instr q=1 adds 512

#define STAGE_A1(buf, ks, kt)                                                    \
    { GL16(gAb + (size_t)(kt) * 64 + (ks) * 32, &alds[buf][ks][ldst]);           \
      GL16(gAb + (size_t)16 * K + (size_t)(kt) * 64 + (ks) * 32,                 \
           &alds[buf][ks][ldst + 512]); }
#define STAGE_B1(buf, ks, kt)                                                    \
    { GL16(gBb + (size_t)(kt) * 64 + (ks) * 32, &blds[buf][ks][ldst]);           \
      GL16(gBb + (size_t)16 * K + (size_t)(kt) * 64 + (ks) * 32,                 \
           &blds[buf][ks][ldst + 512]); }

    // reads: row = base16 + li -> stored slot = lg ^ ((li>>1)&3)  (2-way = free)
    const int rslot = (lg ^ ((li >> 1) & 3)) * 8;
#define READ_A(buf, ks, mh)                                                      \
    _Pragma("unroll") for (int m = 0; m < 4; ++m)                                \
        af[m] = *(const bf16x8*)&alds[buf][ks][(wm * 128 + (mh) * 64 + m * 16 + li) * 32 + rslot];
#define READ_B(buf, ks)                                                          \
    _Pragma("unroll") for (int n = 0; n < 4; ++n)                                \
        bfr[n] = *(const bf16x8*)&blds[buf][ks][(wn * 64 + n * 16 + li) * 32 + rslot];
#define MFMA16(mh)                                                               \
    _Pragma("unroll") for (int m = 0; m < 4; ++m)                                \
        _Pragma("unroll") for (int n = 0; n < 4; ++n)                            \
            acc[(mh) * 4 + m][n] = __builtin_amdgcn_mfma_f32_16x16x32_bf16(      \
                af[m], bfr[n], acc[(mh) * 4 + m][n], 0, 0, 0);
#define PH_MFMA(mh)                                                              \
    __builtin_amdgcn_s_barrier();                                                \
    __builtin_amdgcn_s_setprio(1); MFMA16(mh); __builtin_amdgcn_s_setprio(0);    \
    __builtin_amdgcn_s_barrier();
#define W8() asm volatile("s_waitcnt vmcnt(8)" ::: "memory")
#define W4() asm volatile("s_waitcnt vmcnt(4)" ::: "memory")
#define W0() asm volatile("s_waitcnt vmcnt(0)" ::: "memory")

    f32x4 acc[8][4] = {};
    bf16x8 af[4], bfr[4];

    // prologue: tile0 both halves -> buf0 (8), tile1.ks0 -> buf1 (4)
    STAGE_A1(0, 0, 0); STAGE_B1(0, 0, 0);
    STAGE_A1(0, 1, 0); STAGE_B1(0, 1, 0);
    STAGE_A1(1, 0, 1); STAGE_B1(1, 0, 1);
    W4();                              // buf0 landed; buf1.ks0 (4) in flight
    __builtin_amdgcn_s_barrier();

    // main loop: 7 full iterations (K=1024 -> 16 K-tiles -> 8 iters, last peeled)
    for (int i = 0; i < 7; ++i) {
        const int t1 = 2 * i + 1, t2 = 2 * i + 2, t3 = 2 * i + 3;
        READ_A(0, 0, 0); READ_B(0, 0); STAGE_A1(1, 1, t1);        PH_MFMA(0);  // P1
        READ_A(0, 0, 1);               STAGE_B1(1, 1, t1); W8();  PH_MFMA(1);  // P2
        READ_A(0, 1, 0); READ_B(0, 1); STAGE_A1(0, 0, t2);        PH_MFMA(0);  // P3
        READ_A(0, 1, 1);               STAGE_B1(0, 0, t2); W8();  PH_MFMA(1);  // P4
        READ_A(1, 0, 0); READ_B(1, 0); STAGE_A1(0, 1, t2);        PH_MFMA(0);  // P5
        READ_A(1, 0, 1);               STAGE_B1(0, 1, t2); W8();  PH_MFMA(1);  // P6
        READ_A(1, 1, 0); READ_B(1, 1); STAGE_A1(1, 0, t3);        PH_MFMA(0);  // P7
        READ_A(1, 1, 1);               STAGE_B1(1, 0, t3); W8();  PH_MFMA(1);  // P8
    }
    // peeled last iteration (t1 = 15; no t2/t3 stages; drain 8 -> 4 -> 0)
    {
        READ_A(0, 0, 0); READ_B(0, 0); STAGE_A1(1, 1, 15);        PH_MFMA(0);  // P1
        READ_A(0, 0, 1);               STAGE_B1(1, 1, 15); W8();  PH_MFMA(1);  // P2
        READ_A(0, 1, 0); READ_B(0, 1);                            PH_MFMA(0);  // P3
        READ_A(0, 1, 1);                                   W4();  PH_MFMA(1);  // P4
        READ_A(1, 0, 0); READ_B(1, 0);                            PH_MFMA(0);  // P5
        READ_A(1, 0, 1);                                   W0();  PH_MFMA(1);  // P6
        READ_A(1, 1, 0); READ_B(1, 1);                            PH_MFMA(0);  // P7
        READ_A(1, 1, 1);                                          PH_MFMA(1);  // P8
    }

#pragma unroll
    for (int mr = 0; mr < 8; ++mr)
#pragma unroll
        for (int nr = 0; nr < 4; ++nr)
#pragma unroll
            for (int rr = 0; rr < 4; ++rr) {
                int row = m0 + wm * 128 + mr * 16 + lg * 4 + rr;
                int col = n0 + wn * 64 + nr * 16 + li;
                Cb[(size_t)row * N + col] = f2bf(acc[mr][nr][rr]);
            }
#undef STAGE_A1
#undef STAGE_B1
#undef READ_A
#undef READ_B
#undef MFMA16
#undef PH_MFMA
#undef W8
#undef W4
#undef W0
}

// ---------------- gemm2: X = attn_vec x Wo^T + h (f32 out), 2-phase 128² ----------
__global__ __launch_bounds__(256) void gemm_bt_kernel(
        const u16* __restrict__ A, const u16* __restrict__ Bt,
        const float* __restrict__ H, float* __restrict__ X,
        int M, int N, int K) {
    constexpr int LDT = 40;                 // 32 + 8 pad
    __shared__ u16 alds[2][128 * LDT];
    __shared__ u16 blds[2][128 * LDT];
    const int t = threadIdx.x;
    const int lane = t & 63;
    const int wave = t >> 6;
    const int wm = wave >> 1, wn = wave & 1;
    const int m0 = blockIdx.x * 128;
    const int n0 = blockIdx.y * 128;
    const int nk = K >> 5;

    const int srow = t >> 1;
    const int sch = (t & 1) * 2;
    const u16* ga = A + (size_t)(m0 + srow) * K + sch * 8;
    const u16* gb = Bt + (size_t)(n0 + srow) * K + sch * 8;
    const int wo = srow * LDT + sch * 8;

    u16x8 ra0 = *(const u16x8*)(ga);
    u16x8 ra1 = *(const u16x8*)(ga + 8);
    u16x8 rb0 = *(const u16x8*)(gb);
    u16x8 rb1 = *(const u16x8*)(gb + 8);
    *(u16x8*)&alds[0][wo] = ra0;  *(u16x8*)&alds[0][wo + 8] = ra1;
    *(u16x8*)&blds[0][wo] = rb0;  *(u16x8*)&blds[0][wo + 8] = rb1;

    f32x4 acc[4][4] = {};
    const int ko = (lane >> 4) * 8;
    const int arow_base = wm * 64 + (lane & 15);
    const int brow_base = wn * 64 + (lane & 15);

    int cur = 0;
    for (int kt = 0; kt < nk; ++kt) {
        __syncthreads();
        if (kt + 1 < nk) {
            const u16* gan = ga + (kt + 1) * 32;
            const u16* gbn = gb + (kt + 1) * 32;
            ra0 = *(const u16x8*)(gan);
            ra1 = *(const u16x8*)(gan + 8);
            rb0 = *(const u16x8*)(gbn);
            rb1 = *(const u16x8*)(gbn + 8);
        }
        bf16x8 afrag[4], bfrag[4];
#pragma unroll
        for (int m = 0; m < 4; ++m)
            afrag[m] = *(const bf16x8*)&alds[cur][(arow_base + m * 16) * LDT + ko];
#pragma unroll
        for (int n = 0; n < 4; ++n)
            bfrag[n] = *(const bf16x8*)&blds[cur][(brow_base + n * 16) * LDT + ko];
#pragma unroll
        for (int m = 0; m < 4; ++m)
#pragma unroll
            for (int n = 0; n < 4; ++n)
                acc[m][n] = __builtin_amdgcn_mfma_f32_16x16x32_bf16(afrag[m], bfrag[n],
                                                                   acc[m][n], 0, 0, 0);
        if (kt + 1 < nk) {
            *(u16x8*)&alds[cur ^ 1][wo] = ra0;  *(u16x8*)&alds[cur ^ 1][wo + 8] = ra1;
            *(u16x8*)&blds[cur ^ 1][wo] = rb0;  *(u16x8*)&blds[cur ^ 1][wo + 8] = rb1;
        }
        cur ^= 1;
    }

#pragma unroll
    for (int m = 0; m < 4; ++m)
#pragma unroll
        for (int n = 0; n < 4; ++n)
#pragma unroll
            for (int r = 0; r < 4; ++r) {
                int row = m0 + wm * 64 + m * 16 + (lane >> 4) * 4 + r;
                int col = n0 + wn * 64 + n * 16 + (lane & 15);
                size_t idx = (size_t)row * N + col;
                X[idx] = acc[m][n][r] + H[idx];
            }
}

// ---------------- V transpose ----------------
__global__ __launch_bounds__(256) void transpose_v_kernel(const u16* __restrict__ qkvb,
                                                          u16* __restrict__ vt) {
    __shared__ u16 tl[64][72];
    const int t = threadIdx.x;
    const int p = blockIdx.y;
    const int nn = p >> 1, b = p & 1;
    const int s0 = blockIdx.x * 64;
    const int r = t >> 2;
    const int ch = (t & 3) * 2;
    const u16* g = qkvb + ((size_t)(s0 + r) * 2 + b) * 3072 + 2048 + nn * 64;
    *(u16x8*)&tl[r][ch * 8]     = *(const u16x8*)(g + ch * 8);
    *(u16x8*)&tl[r][ch * 8 + 8] = *(const u16x8*)(g + ch * 8 + 8);
    __syncthreads();
    const int dh = t >> 2;
    const int sc = (t & 3) * 2;
    u16* o = vt + ((size_t)p * 64 + dh) * 2048 + s0;
#pragma unroll
    for (int q = 0; q < 2; ++q) {
        int scq = sc + q;
        u16x8 v;
#pragma unroll
        for (int j = 0; j < 8; ++j) v[j] = tl[scq * 8 + j][dh];
        *(u16x8*)(o + scq * 8) = v;
    }
}

// ---------------- causal flash attention (r5-proven structure) ----------------
__global__ __launch_bounds__(256) void attn_kernel(const u16* __restrict__ qkvb,
                                                   const u16* __restrict__ vt,
                                                   u16* __restrict__ attnb) {
    constexpr int LKT = 72;               // 64 + 8 pad
    __shared__ u16 klds[2][64 * LKT];
    __shared__ u16 vlds[2][64 * LKT];
#if !USE_PERMLANE
    __shared__ u16 plds[4][16 * LKT];
#endif
    const int t = threadIdx.x;
    const int lane = t & 63;
    const int w = t >> 6;
    const int bid = blockIdx.x;
    const int g = bid >> 5;               // 0..31
    const int sq = g & 7, jq = g >> 3;
    const int qt = (jq == 0) ? (31 - sq) : (jq == 1) ? (16 + sq)
                 : (jq == 2) ? (15 - sq) : sq;
    const int p = bid & 31;
    const int nn = p >> 1, b = p & 1;
    const int i0 = qt * 64;

    const int li = lane & 15;
    const int lg = lane >> 4;

    const int qrow = i0 + w * 16 + li;
    const u16* qg = qkvb + ((size_t)qrow * 2 + b) * 3072 + nn * 64 + lg * 8;
    bf16x8 qa0 = *(const bf16x8*)(qg);
    bf16x8 qa1 = *(const bf16x8*)(qg + 32);

    f32x4 o[4] = {};
    float mrun = -3.0e38f;
    float lrun = 0.f;

    const int srow = t >> 2;
    const int sch = (t & 3) * 2;
    const u16* kg = qkvb + 1024 + nn * 64 + sch * 8;
    const u16* vg = vt + ((size_t)p * 64 + srow) * 2048 + sch * 8;
    const int swo = srow * LKT + sch * 8;

    const int nt = qt + 1;
    u16x8 k0, k1, v0, v1;
    {
        const u16* kgp = kg + ((size_t)srow * 2 + b) * 3072;
        k0 = *(const u16x8*)(kgp);  k1 = *(const u16x8*)(kgp + 8);
        v0 = *(const u16x8*)(vg);   v1 = *(const u16x8*)(vg + 8);
    }
    *(u16x8*)&klds[0][swo] = k0;  *(u16x8*)&klds[0][swo + 8] = k1;
    *(u16x8*)&vlds[0][swo] = v0;  *(u16x8*)&vlds[0][swo + 8] = v1;
    __syncthreads();

    for (int jt = 0; jt < nt; ++jt) {
        const int buf = jt & 1;
        if (jt + 1 < nt) {
            const u16* kgp = kg + ((size_t)(jt * 64 + 64 + srow) * 2 + b) * 3072;
            k0 = *(const u16x8*)(kgp);  k1 = *(const u16x8*)(kgp + 8);
            const u16* vgp = vg + jt * 64 + 64;
            v0 = *(const u16x8*)(vgp);  v1 = *(const u16x8*)(vgp + 8);
        }

        f32x4 st[4];
        __builtin_amdgcn_s_setprio(1);
#pragma unroll
        for (int cf = 0; cf < 4; ++cf) {
            bf16x8 kb0 = *(const bf16x8*)&klds[buf][(cf * 16 + li) * LKT + lg * 8];
            bf16x8 kb1 = *(const bf16x8*)&klds[buf][(cf * 16 + li) * LKT + 32 + lg * 8];
            f32x4 z = {};
            z = __builtin_amdgcn_mfma_f32_16x16x32_bf16(kb0, qa0, z, 0, 0, 0);
            z = __builtin_amdgcn_mfma_f32_16x16x32_bf16(kb1, qa1, z, 0, 0, 0);
            st[cf] = z;
        }
        __builtin_amdgcn_s_setprio(0);

        if (jt == qt) {
            const int it = w * 16 + li;
#pragma unroll
            for (int cf = 0; cf < 4; ++cf)
#pragma unroll
                for (int r = 0; r < 4; ++r) {
                    int jl = cf * 16 + lg * 4 + r;
                    if (jl > it) st[cf][r] = -3.0e38f;
                }
        }

        float mloc = st[0][0];
#pragma unroll
        for (int cf = 0; cf < 4; ++cf)
#pragma unroll
            for (int r = 0; r < 4; ++r) mloc = fmaxf(mloc, st[cf][r]);
        mloc = fmaxf(mloc, __shfl_xor(mloc, 16, 64));
        mloc = fmaxf(mloc, __shfl_xor(mloc, 32, 64));

        if (__any(mloc > mrun + 8.0f)) {
            float mnew = fmaxf(mrun, mloc);
            float alpha = fexp2(mrun - mnew);
            lrun *= alpha;
            mrun = mnew;
#pragma unroll
            for (int r = 0; r < 4; ++r) {
                float ar = __shfl(alpha, lg * 4 + r, 64);
#pragma unroll
                for (int cf = 0; cf < 4; ++cf) o[cf][r] *= ar;
            }
        }

#if USE_PERMLANE
        float rsum = 0.f;
        u32 wv[4][2];
#pragma unroll
        for (int cf = 0; cf < 4; ++cf)
#pragma unroll
            for (int rr = 0; rr < 2; ++rr) {
                float p0 = fexp2(st[cf][2 * rr] - mrun);
                float p1 = fexp2(st[cf][2 * rr + 1] - mrun);
                rsum += p0 + p1;
                u32 wres;
                asm("v_cvt_pk_bf16_f32 %0, %1, %2" : "=v"(wres) : "v"(p0), "v"(p1));
                wv[cf][rr] = wres;
            }
        rsum += __shfl_xor(rsum, 16, 64);
        rsum += __shfl_xor(rsum, 32, 64);
        lrun += rsum;

        __builtin_amdgcn_s_setprio(1);
#pragma unroll
        for (int ks = 0; ks < 2; ++ks) {
            u32x2 sa = __builtin_amdgcn_permlane32_swap(wv[2 * ks][0], wv[2 * ks + 1][0], false, false);
            u32x2 fa = __builtin_amdgcn_permlane16_swap(sa[0], sa[1], false, false);
            u32x2 sb = __builtin_amdgcn_permlane32_swap(wv[2 * ks][1], wv[2 * ks + 1][1], false, false);
            u32x2 fb = __builtin_amdgcn_permlane16_swap(sb[0], sb[1], false, false);
            u32x4 fw = { fa[0], fb[0], fa[1], fb[1] };
            bf16x8 pa = __builtin_bit_cast(bf16x8, fw);
#pragma unroll
            for (int cf = 0; cf < 4; ++cf) {
                bf16x8 vb = *(const bf16x8*)&vlds[buf][(cf * 16 + li) * LKT + ks * 32 + lg * 8];
                o[cf] = __builtin_amdgcn_mfma_f32_16x16x32_bf16(pa, vb, o[cf], 0, 0, 0);
            }
        }
        __builtin_amdgcn_s_setprio(0);
#else
        float rsum = 0.f;
#pragma unroll
        for (int cf = 0; cf < 4; ++cf) {
            u16x4 pw;
#pragma unroll
            for (int r = 0; r < 4; ++r) {
                float pv = fexp2(st[cf][r] - mrun);
                rsum += pv;
                pw[r] = f2bf(pv);
            }
            *(u16x4*)&plds[w][li * LKT + cf * 16 + lg * 4] = pw;
        }
        rsum += __shfl_xor(rsum, 16, 64);
        rsum += __shfl_xor(rsum, 32, 64);
        lrun += rsum;

        asm volatile("s_waitcnt lgkmcnt(0)" ::: "memory");
        __builtin_amdgcn_sched_barrier(0);

#pragma unroll
        for (int ks = 0; ks < 2; ++ks) {
            bf16x8 pa = *(const bf16x8*)&plds[w][li * LKT + ks * 32 + lg * 8];
#pragma unroll
            for (int cf = 0; cf < 4; ++cf) {
                bf16x8 vb = *(const bf16x8*)&vlds[buf][(cf * 16 + li) * LKT + ks * 32 + lg * 8];
                o[cf] = __builtin_amdgcn_mfma_f32_16x16x32_bf16(pa, vb, o[cf], 0, 0, 0);
            }
        }
#endif

        if (jt + 1 < nt) {
            *(u16x8*)&klds[buf ^ 1][swo] = k0;  *(u16x8*)&klds[buf ^ 1][swo + 8] = k1;
            *(u16x8*)&vlds[buf ^ 1][swo] = v0;  *(u16x8*)&vlds[buf ^ 1][swo + 8] = v1;
        }
        __syncthreads();
    }

    float rinv = frcp(lrun);
#pragma unroll
    for (int r = 0; r < 4; ++r) {
        float rv = __shfl(rinv, lg * 4 + r, 64);
        int srowg = i0 + w * 16 + lg * 4 + r;
        u16* og = attnb + ((size_t)srowg * 2 + b) * 1024 + nn * 64;
#pragma unroll
        for (int cf = 0; cf < 4; ++cf)
            og[cf * 16 + li] = f2bf(o[cf][r] * rv);
    }
}

// ---------------- residual LayerNorm ----------------
__global__ __launch_bounds__(256) void ln_kernel(const float* __restrict__ X,
                                                 const float* __restrict__ gamma,
                                                 const float* __restrict__ beta,
                                                 float* __restrict__ out) {
    __shared__ float red[8];
    const int t = threadIdx.x;
    const int row = blockIdx.x;
    float4 v = ((const float4*)(X + (size_t)row * 1024))[t];
    float s = v.x + v.y + v.z + v.w;
#pragma unroll
    for (int off = 1; off < 64; off <<= 1) s += __shfl_xor(s, off, 64);
    if ((t & 63) == 0) red[t >> 6] = s;
    __syncthreads();
    float mu = (red[0] + red[1] + red[2] + red[3]) * (1.f / 1024.f);
    float dx = v.x - mu, dy = v.y - mu, dz = v.z - mu, dw = v.w - mu;
    float q = dx * dx + dy * dy + dz * dz + dw * dw;
#pragma unroll
    for (int off = 1; off < 64; off <<= 1) q += __shfl_xor(q, off, 64);
    if ((t & 63) == 0) red[4 + (t >> 6)] = q;
    __syncthreads();
    float var = (red[4] + red[5] + red[6] + red[7]) * (1.f / 1024.f);
    float rs = rsqrtf(var + 1e-5f);
    float4 g = ((const float4*)gamma)[t];
    float4 bt = ((const float4*)beta)[t];
    float4 o;
    o.x = dx * rs * g.x + bt.x;
    o.y = dy * rs * g.y + bt.y;
    o.z = dz * rs * g.z + bt.z;
    o.w = dw * rs * g.w + bt.w;
    ((float4*)(out + (size_t)row * 1024))[t] = o;
}

// ---------------- launch ----------------
extern "C" void kernel_launch(void* const* d_in, const int* in_sizes, int n_in,
                              void* d_out, int out_size, void* d_ws, size_t ws_size,
                              hipStream_t stream) {
    const float* h     = (const float*)d_in[0];
    // d_in[1] = attn_mask (deterministic causal triu; applied analytically)
    const float* Wqkv  = (const float*)d_in[2];
    const float* Wo    = (const float*)d_in[3];
    const float* gamma = (const float*)d_in[4];
    const float* beta  = (const float*)d_in[5];
    float* out = (float*)d_out;

    char* ws = (char*)d_ws;
    u16*   hb    = (u16*)(ws);
    u16*   wqkvt = (u16*)(ws + 8388608);
    u16*   wot   = (u16*)(ws + 14680064);
    u16*   qkvb  = (u16*)(ws + 16777216);
    u16*   vt    = (u16*)(ws + 41943040);
    u16*   attnb = (u16*)(ws + 50331648);
    float* xbuf  = (float*)(ws + 58720256);

    const float qscale = 0.125f * 1.44269504088896f;  // 1/sqrt(Dh) * log2(e)

    conv_h_kernel<<<4096, 256, 0, stream>>>(h, hb);
    conv_wt_kernel<<<dim3(96, 32), 256, 0, stream>>>(Wqkv, wqkvt, 1024, 3072, 1024, qscale);
    conv_wt_kernel<<<dim3(32, 32), 256, 0, stream>>>(Wo, wot, 1024, 1024, 0, 1.0f);
    gemm1_8ph_kernel<<<192, 512, 0, stream>>>(hb, wqkvt, qkvb, 4096, 3072, 1024);
    transpose_v_kernel<<<dim3(32, 32), 256, 0, stream>>>(qkvb, vt);
    attn_kernel<<<1024, 256, 0, stream>>>(qkvb, vt, attnb);
    gemm_bt_kernel<<<dim3(32, 8), 256, 0, stream>>>(attnb, wot, h, xbuf, 4096, 1024, 1024);
    ln_kernel<<<4096, 256, 0, stream>>>(xbuf, gamma, beta, out);
}

// Round 15
// 117.057 us; speedup vs baseline: 1.1548x; 1.0485x over previous
//
#include <hip/hip_runtime.h>

// CONVERGED PORTFOLIO (r8 config, session-best 117.33 us).
// Falsified alternatives (do not retry without new evidence):
//  - gemm1 8-phase 256x256 (r12/r14): barrier-structural stall at K=1024, 1 blk/CU
//    (490 TF vs 570 TF 2-phase) even with 0 bank conflicts + counted vmcnt(8).
//  - conv_h fused into gemm1 staging (r13): +6.3M bank conflicts, 57.5 us.
//  - m97 global_load_lds 2-phase (r3): -4 us vs reg-staged at K=1024.
//  - attn without LDS (r6): uncoalesced 12KB-stride lanes, 126 us.
//  - attn k-chunked LDS (r7): chunk stride bank-aligned, conflicts up 50%.
//  - attn 32x32 MFMA (r9-r11): f32x16 regs -> spill at w=4 cap; at w=2, 1 blk/CU
//    TLP-starved (52 us > 45 us).

typedef unsigned short u16;
typedef unsigned int u32;
typedef __attribute__((ext_vector_type(8))) __bf16 bf16x8;
typedef __attribute__((ext_vector_type(4))) float f32x4;
typedef __attribute__((ext_vector_type(8))) unsigned short u16x8;
typedef __attribute__((ext_vector_type(4))) unsigned short u16x4;
typedef __attribute__((ext_vector_type(2))) unsigned int u32x2;
typedef __attribute__((ext_vector_type(4))) unsigned int u32x4;

#if defined(__has_builtin)
#if __has_builtin(__builtin_amdgcn_permlane32_swap) && __has_builtin(__builtin_amdgcn_permlane16_swap)
#define USE_PERMLANE 1
#endif
#endif
#ifndef USE_PERMLANE
#define USE_PERMLANE 0
#endif

__device__ __forceinline__ u16 f2bf(float f) {
    u32 u = __builtin_bit_cast(u32, f);
    u += 0x7fffu + ((u >> 16) & 1u);   // round-to-nearest-even
    return (u16)(u >> 16);
}

__device__ __forceinline__ float fexp2(float x) {
#if __has_builtin(__builtin_amdgcn_exp2f)
    return __builtin_amdgcn_exp2f(x);
#else
    return exp2f(x);
#endif
}

__device__ __forceinline__ float frcp(float x) {
#if __has_builtin(__builtin_amdgcn_rcpf)
    return __builtin_amdgcn_rcpf(x);
#else
    return 1.0f / x;
#endif
}

// ---------------- conversions ----------------
__global__ __launch_bounds__(256) void conv_h_kernel(const float* __restrict__ h,
                                                     u16* __restrict__ hb) {
    int i = blockIdx.x * 256 + threadIdx.x;
    float4 v = ((const float4*)h)[i];
    u16x4 o = { f2bf(v.x), f2bf(v.y), f2bf(v.z), f2bf(v.w) };
    ((u16x4*)hb)[i] = o;
}

// W [R][C] f32 -> Wt [C][R] bf16 (transpose + convert); rows < scale_rows get *scale
__global__ __launch_bounds__(256) void conv_wt_kernel(const float* __restrict__ W,
                                                      u16* __restrict__ Wt,
                                                      int R, int C,
                                                      int scale_rows, float scale) {
    __shared__ float tile[32][33];
    int t = threadIdx.x;
    int r = t >> 3, c4 = (t & 7) * 4;
    int gx = blockIdx.x * 32, gy = blockIdx.y * 32;
    float4 v = *(const float4*)&W[(size_t)(gy + r) * C + gx + c4];
    tile[r][c4 + 0] = v.x; tile[r][c4 + 1] = v.y;
    tile[r][c4 + 2] = v.z; tile[r][c4 + 3] = v.w;
    __syncthreads();
    float sc = (gx + r < scale_rows) ? scale : 1.0f;
    u16x4 o = { f2bf(tile[c4 + 0][r] * sc), f2bf(tile[c4 + 1][r] * sc),
                f2bf(tile[c4 + 2][r] * sc), f2bf(tile[c4 + 3][r] * sc) };
    *(u16x4*)&Wt[(size_t)(gx + r) * R + gy + c4] = o;
}

// ---------------- GEMM: C[M][N] = A[M][K] (bf16) x Bt[N][K]^T (bf16) ----------------
// reg-staged 2-phase, padded LDS (proven structure; ~570 TF at this shape)
template <int MODE>
__global__ __launch_bounds__(256) void gemm_bt_kernel(
        const u16* __restrict__ A, const u16* __restrict__ Bt,
        u16* __restrict__ Cb, const float* __restrict__ H, float* __restrict__ X,
        int M, int N, int K) {
    constexpr int LDT = 40;                 // 32 + 8 pad
    __shared__ u16 alds[2][128 * LDT];
    __shared__ u16 blds[2][128 * LDT];
    const int t = threadIdx.x;
    const int lane = t & 63;
    const int wave = t >> 6;
    const int wm = wave >> 1, wn = wave & 1;
    const int m0 = blockIdx.x * 128;
    const int n0 = blockIdx.y * 128;
    const int nk = K >> 5;

    const int srow = t >> 1;
    const int sch = (t & 1) * 2;
    const u16* ga = A + (size_t)(m0 + srow) * K + sch * 8;
    const u16* gb = Bt + (size_t)(n0 + srow) * K + sch * 8;
    const int wo = srow * LDT + sch * 8;

    u16x8 ra0 = *(const u16x8*)(ga);
    u16x8 ra1 = *(const u16x8*)(ga + 8);
    u16x8 rb0 = *(const u16x8*)(gb);
    u16x8 rb1 = *(const u16x8*)(gb + 8);
    *(u16x8*)&alds[0][wo] = ra0;  *(u16x8*)&alds[0][wo + 8] = ra1;
    *(u16x8*)&blds[0][wo] = rb0;  *(u16x8*)&blds[0][wo + 8] = rb1;

    f32x4 acc[4][4] = {};
    const int ko = (lane >> 4) * 8;
    const int arow_base = wm * 64 + (lane & 15);
    const int brow_base = wn * 64 + (lane & 15);

    int cur = 0;
    for (int kt = 0; kt < nk; ++kt) {
        __syncthreads();
        if (kt + 1 < nk) {
            const u16* gan = ga + (kt + 1) * 32;
            const u16* gbn = gb + (kt + 1) * 32;
            ra0 = *(const u16x8*)(gan);
            ra1 = *(const u16x8*)(gan + 8);
            rb0 = *(const u16x8*)(gbn);
            rb1 = *(const u16x8*)(gbn + 8);
        }
        bf16x8 afrag[4], bfrag[4];
#pragma unroll
        for (int m = 0; m < 4; ++m)
            afrag[m] = *(const bf16x8*)&alds[cur][(arow_base + m * 16) * LDT + ko];
#pragma unroll
        for (int n = 0; n < 4; ++n)
            bfrag[n] = *(const bf16x8*)&blds[cur][(brow_base + n * 16) * LDT + ko];
#pragma unroll
        for (int m = 0; m < 4; ++m)
#pragma unroll
            for (int n = 0; n < 4; ++n)
                acc[m][n] = __builtin_amdgcn_mfma_f32_16x16x32_bf16(afrag[m], bfrag[n],
                                                                   acc[m][n], 0, 0, 0);
        if (kt + 1 < nk) {
            *(u16x8*)&alds[cur ^ 1][wo] = ra0;  *(u16x8*)&alds[cur ^ 1][wo + 8] = ra1;
            *(u16x8*)&blds[cur ^ 1][wo] = rb0;  *(u16x8*)&blds[cur ^ 1][wo + 8] = rb1;
        }
        cur ^= 1;
    }

#pragma unroll
    for (int m = 0; m < 4; ++m)
#pragma unroll
        for (int n = 0; n < 4; ++n)
#pragma unroll
            for (int r = 0; r < 4; ++r) {
                int row = m0 + wm * 64 + m * 16 + (lane >> 4) * 4 + r;
                int col = n0 + wn * 64 + n * 16 + (lane & 15);
                size_t idx = (size_t)row * N + col;
                if (MODE == 0) Cb[idx] = f2bf(acc[m][n][r]);
                else           X[idx] = acc[m][n][r] + H[idx];
            }
}

// ---------------- V transpose ----------------
__global__ __launch_bounds__(256) void transpose_v_kernel(const u16* __restrict__ qkvb,
                                                          u16* __restrict__ vt) {
    __shared__ u16 tl[64][72];
    const int t = threadIdx.x;
    const int p = blockIdx.y;
    const int nn = p >> 1, b = p & 1;
    const int s0 = blockIdx.x * 64;
    const int r = t >> 2;
    const int ch = (t & 3) * 2;
    const u16* g = qkvb + ((size_t)(s0 + r) * 2 + b) * 3072 + 2048 + nn * 64;
    *(u16x8*)&tl[r][ch * 8]     = *(const u16x8*)(g + ch * 8);
    *(u16x8*)&tl[r][ch * 8 + 8] = *(const u16x8*)(g + ch * 8 + 8);
    __syncthreads();
    const int dh = t >> 2;
    const int sc = (t & 3) * 2;
    u16* o = vt + ((size_t)p * 64 + dh) * 2048 + s0;
#pragma unroll
    for (int q = 0; q < 2; ++q) {
        int scq = sc + q;
        u16x8 v;
#pragma unroll
        for (int j = 0; j < 8; ++j) v[j] = tl[scq * 8 + j][dh];
        *(u16x8*)(o + scq * 8) = v;
    }
}

// ---------------- causal flash attention (split-j, 8 waves) ----------------
// 2 wave-groups per block: group 0 = even j-tiles, group 1 = odd j-tiles, each with
// private double-buffered K/V LDS (swapped QK^T in exp2 units, permlane P-exchange,
// defer-rescale). Groups merge partials in LDS at end. Session-best: 45.0 us.
__global__ __launch_bounds__(512) void attn_kernel(const u16* __restrict__ qkvb,
                                                   const u16* __restrict__ vt,
                                                   u16* __restrict__ attnb) {
    constexpr int LKT = 72;               // 64 + 8 pad
    __shared__ u16 kvs[2][2][2][64 * LKT];   // [group][buf][K/V][row*LKT + col]
#if !USE_PERMLANE
    __shared__ u16 plds[8][16 * LKT];
#endif
    const int t = threadIdx.x;
    const int lane = t & 63;
    const int w = (t >> 6) & 3;           // wave within group
    const int grp = t >> 8;               // 0: even jt, 1: odd jt
    const int bid = blockIdx.x;
    const int qt = 31 - (bid >> 5);       // heavy q-tiles dispatched first
    const int p = bid & 31;
    const int nn = p >> 1, b = p & 1;
    const int i0 = qt * 64;

    const int li = lane & 15;
    const int lg = lane >> 4;

    // Q fragments (B-operand rows i = i0 + w*16 + li) — identical for both groups
    const int qrow = i0 + w * 16 + li;
    const u16* qg = qkvb + ((size_t)qrow * 2 + b) * 3072 + nn * 64 + lg * 8;
    bf16x8 qa0 = *(const bf16x8*)(qg);
    bf16x8 qa1 = *(const bf16x8*)(qg + 32);

    f32x4 o[4] = {};                      // O[row = lg*4+r][d = cf*16+li]
    float mrun = -3.0e38f;
    float lrun = 0.f;

    // staging geometry (group-local 256 threads)
    const int tg = t & 255;
    const int srow = tg >> 2;             // 0..63
    const int sch = (tg & 3) * 2;
    const u16* kg = qkvb + 1024 + nn * 64 + sch * 8;
    const u16* vg = vt + ((size_t)p * 64 + srow) * 2048 + sch * 8;
    const int swo = srow * LKT + sch * 8;

    const int nt = qt + 1;
    const int G = (nt + 1) >> 1;          // rounds per group

    u16x8 k0, k1, v0, v1;
    if (grp < nt) {                       // stage my first tile (jt = grp)
        const u16* kgp = kg + ((size_t)(grp * 64 + srow) * 2 + b) * 3072;
        k0 = *(const u16x8*)(kgp);  k1 = *(const u16x8*)(kgp + 8);
        const u16* vgp = vg + grp * 64;
        v0 = *(const u16x8*)(vgp);  v1 = *(const u16x8*)(vgp + 8);
        *(u16x8*)&kvs[grp][0][0][swo] = k0;  *(u16x8*)&kvs[grp][0][0][swo + 8] = k1;
        *(u16x8*)&kvs[grp][0][1][swo] = v0;  *(u16x8*)&kvs[grp][0][1][swo + 8] = v1;
    }
    __syncthreads();

    for (int s = 0; s < G; ++s) {
        const int jt = 2 * s + grp;
        const int buf = s & 1;
        const bool active = jt < nt;      // only group 1's last round can be inactive
        if (jt + 2 < nt) {                // issue-early my next tile
            const u16* kgp = kg + ((size_t)((jt + 2) * 64 + srow) * 2 + b) * 3072;
            k0 = *(const u16x8*)(kgp);  k1 = *(const u16x8*)(kgp + 8);
            const u16* vgp = vg + (jt + 2) * 64;
            v0 = *(const u16x8*)(vgp);  v1 = *(const u16x8*)(vgp + 8);
        }

        if (active) {
            const u16* kl = &kvs[grp][buf][0][0];
            const u16* vl = &kvs[grp][buf][1][0];

            // swapped QK^T: st[cf][r] = S^T[j = jt*64+cf*16+lg*4+r][i = i0+w*16+li]
            f32x4 st[4];
            __builtin_amdgcn_s_setprio(1);
#pragma unroll
            for (int cf = 0; cf < 4; ++cf) {
                bf16x8 kb0 = *(const bf16x8*)&kl[(cf * 16 + li) * LKT + lg * 8];
                bf16x8 kb1 = *(const bf16x8*)&kl[(cf * 16 + li) * LKT + 32 + lg * 8];
                f32x4 z = {};
                z = __builtin_amdgcn_mfma_f32_16x16x32_bf16(kb0, qa0, z, 0, 0, 0);
                z = __builtin_amdgcn_mfma_f32_16x16x32_bf16(kb1, qa1, z, 0, 0, 0);
                st[cf] = z;
            }
            __builtin_amdgcn_s_setprio(0);

            if (jt == qt) {               // mask only the diagonal tile
                const int it = w * 16 + li;
#pragma unroll
                for (int cf = 0; cf < 4; ++cf)
#pragma unroll
                    for (int r = 0; r < 4; ++r) {
                        int jl = cf * 16 + lg * 4 + r;
                        if (jl > it) st[cf][r] = -3.0e38f;
                    }
            }

            // row max: 15 in-reg + 2 shuffles
            float mloc = st[0][0];
#pragma unroll
            for (int cf = 0; cf < 4; ++cf)
#pragma unroll
                for (int r = 0; r < 4; ++r) mloc = fmaxf(mloc, st[cf][r]);
            mloc = fmaxf(mloc, __shfl_xor(mloc, 16, 64));
            mloc = fmaxf(mloc, __shfl_xor(mloc, 32, 64));

            // defer-rescale (T13)
            if (__any(mloc > mrun + 8.0f)) {
                float mnew = fmaxf(mrun, mloc);
                float alpha = fexp2(mrun - mnew);
                lrun *= alpha;
                mrun = mnew;
#pragma unroll
                for (int r = 0; r < 4; ++r) {
                    float ar = __shfl(alpha, lg * 4 + r, 64);
#pragma unroll
                    for (int cf = 0; cf < 4; ++cf) o[cf][r] *= ar;
                }
            }

#if USE_PERMLANE
            float rsum = 0.f;
            u32 wv[4][2];
#pragma unroll
            for (int cf = 0; cf < 4; ++cf)
#pragma unroll
                for (int rr = 0; rr < 2; ++rr) {
                    float p0 = fexp2(st[cf][2 * rr] - mrun);
                    float p1 = fexp2(st[cf][2 * rr + 1] - mrun);
                    rsum += p0 + p1;
                    u32 wres;
                    asm("v_cvt_pk_bf16_f32 %0, %1, %2" : "=v"(wres) : "v"(p0), "v"(p1));
                    wv[cf][rr] = wres;
                }
            rsum += __shfl_xor(rsum, 16, 64);
            rsum += __shfl_xor(rsum, 32, 64);
            lrun += rsum;

            __builtin_amdgcn_s_setprio(1);
#pragma unroll
            for (int ks = 0; ks < 2; ++ks) {
                u32x2 sa = __builtin_amdgcn_permlane32_swap(wv[2 * ks][0], wv[2 * ks + 1][0], false, false);
                u32x2 fa = __builtin_amdgcn_permlane16_swap(sa[0], sa[1], false, false);
                u32x2 sb = __builtin_amdgcn_permlane32_swap(wv[2 * ks][1], wv[2 * ks + 1][1], false, false);
                u32x2 fb = __builtin_amdgcn_permlane16_swap(sb[0], sb[1], false, false);
                u32x4 fw = { fa[0], fb[0], fa[1], fb[1] };
                bf16x8 pa = __builtin_bit_cast(bf16x8, fw);
#pragma unroll
                for (int cf = 0; cf < 4; ++cf) {
                    bf16x8 vb = *(const bf16x8*)&vl[(cf * 16 + li) * LKT + ks * 32 + lg * 8];
                    o[cf] = __builtin_amdgcn_mfma_f32_16x16x32_bf16(pa, vb, o[cf], 0, 0, 0);
                }
            }
            __builtin_amdgcn_s_setprio(0);
#else
            float rsum = 0.f;
#pragma unroll
            for (int cf = 0; cf < 4; ++cf) {
                u16x4 pw;
#pragma unroll
                for (int r = 0; r < 4; ++r) {
                    float pv = fexp2(st[cf][r] - mrun);
                    rsum += pv;
                    pw[r] = f2bf(pv);
                }
                *(u16x4*)&plds[t >> 6][li * LKT + cf * 16 + lg * 4] = pw;
            }
            rsum += __shfl_xor(rsum, 16, 64);
            rsum += __shfl_xor(rsum, 32, 64);
            lrun += rsum;

            asm volatile("s_waitcnt lgkmcnt(0)" ::: "memory");
            __builtin_amdgcn_sched_barrier(0);

#pragma unroll
            for (int ks = 0; ks < 2; ++ks) {
                bf16x8 pa = *(const bf16x8*)&plds[t >> 6][li * LKT + ks * 32 + lg * 8];
#pragma unroll
                for (int cf = 0; cf < 4; ++cf) {
                    bf16x8 vb = *(const bf16x8*)&vl[(cf * 16 + li) * LKT + ks * 32 + lg * 8];
                    o[cf] = __builtin_amdgcn_mfma_f32_16x16x32_bf16(pa, vb, o[cf], 0, 0, 0);
                }
            }
#endif
        }

        if (jt + 2 < nt) {                // write-late my next tile into other buffer
            *(u16x8*)&kvs[grp][buf ^ 1][0][swo] = k0;  *(u16x8*)&kvs[grp][buf ^ 1][0][swo + 8] = k1;
            *(u16x8*)&kvs[grp][buf ^ 1][1][swo] = v0;  *(u16x8*)&kvs[grp][buf ^ 1][1][swo + 8] = v1;
        }
        __syncthreads();
    }

    // ---- merge group partials (online-softmax combine) ----
    float* osc = (float*)&kvs[1][0][0][0];       // [64 rows][65] f32
    float* msc = osc + 64 * 65;                  // [64]
    float* lsc = msc + 64;                       // [64]
    if (grp == 1) {
#pragma unroll
        for (int cf = 0; cf < 4; ++cf)
#pragma unroll
            for (int r = 0; r < 4; ++r)
                osc[(w * 16 + lg * 4 + r) * 65 + cf * 16 + li] = o[cf][r];
        if (lg == 0) { msc[w * 16 + li] = mrun; lsc[w * 16 + li] = lrun; }
    }
    __syncthreads();
    if (grp == 0) {
        float mB = msc[w * 16 + li];
        float lB = lsc[w * 16 + li];
        float m = fmaxf(mrun, mB);
        float eA = fexp2(mrun - m);
        float eB = fexp2(mB - m);
        float linv = frcp(lrun * eA + lB * eB);
#pragma unroll
        for (int r = 0; r < 4; ++r) {
            float eAr = __shfl(eA, lg * 4 + r, 64);
            float eBr = __shfl(eB, lg * 4 + r, 64);
            float rvr = __shfl(linv, lg * 4 + r, 64);
            int row = i0 + w * 16 + lg * 4 + r;
            u16* og = attnb + ((size_t)row * 2 + b) * 1024 + nn * 64;
#pragma unroll
            for (int cf = 0; cf < 4; ++cf) {
                float ob = osc[(w * 16 + lg * 4 + r) * 65 + cf * 16 + li];
                og[cf * 16 + li] = f2bf((o[cf][r] * eAr + ob * eBr) * rvr);
            }
        }
    }
}

// ---------------- residual LayerNorm ----------------
__global__ __launch_bounds__(256) void ln_kernel(const float* __restrict__ X,
                                                 const float* __restrict__ gamma,
                                                 const float* __restrict__ beta,
                                                 float* __restrict__ out) {
    __shared__ float red[8];
    const int t = threadIdx.x;
    const int row = blockIdx.x;
    float4 v = ((const float4*)(X + (size_t)row * 1024))[t];
    float s = v.x + v.y + v.z + v.w;
#pragma unroll
    for (int off = 1; off < 64; off <<= 1) s += __shfl_xor(s, off, 64);
    if ((t & 63) == 0) red[t >> 6] = s;
    __syncthreads();
    float mu = (red[0] + red[1] + red[2] + red[3]) * (1.f / 1024.f);
    float dx = v.x - mu, dy = v.y - mu, dz = v.z - mu, dw = v.w - mu;
    float q = dx * dx + dy * dy + dz * dz + dw * dw;
#pragma unroll
    for (int off = 1; off < 64; off <<= 1) q += __shfl_xor(q, off, 64);
    if ((t & 63) == 0) red[4 + (t >> 6)] = q;
    __syncthreads();
    float var = (red[4] + red[5] + red[6] + red[7]) * (1.f / 1024.f);
    float rs = rsqrtf(var + 1e-5f);
    float4 g = ((const float4*)gamma)[t];
    float4 bt = ((const float4*)beta)[t];
    float4 o;
    o.x = dx * rs * g.x + bt.x;
    o.y = dy * rs * g.y + bt.y;
    o.z = dz * rs * g.z + bt.z;
    o.w = dw * rs * g.w + bt.w;
    ((float4*)(out + (size_t)row * 1024))[t] = o;
}

// ---------------- launch ----------------
extern "C" void kernel_launch(void* const* d_in, const int* in_sizes, int n_in,
                              void* d_out, int out_size, void* d_ws, size_t ws_size,
                              hipStream_t stream) {
    const float* h     = (const float*)d_in[0];
    // d_in[1] = attn_mask (deterministic causal triu; applied analytically)
    const float* Wqkv  = (const float*)d_in[2];
    const float* Wo    = (const float*)d_in[3];
    const float* gamma = (const float*)d_in[4];
    const float* beta  = (const float*)d_in[5];
    float* out = (float*)d_out;

    char* ws = (char*)d_ws;
    u16*   hb    = (u16*)(ws);
    u16*   wqkvt = (u16*)(ws + 8388608);
    u16*   wot   = (u16*)(ws + 14680064);
    u16*   qkvb  = (u16*)(ws + 16777216);
    u16*   vt    = (u16*)(ws + 41943040);
    u16*   attnb = (u16*)(ws + 50331648);
    float* xbuf  = (float*)(ws + 58720256);

    const float qscale = 0.125f * 1.44269504088896f;  // 1/sqrt(Dh) * log2(e)

    conv_h_kernel<<<4096, 256, 0, stream>>>(h, hb);
    conv_wt_kernel<<<dim3(96, 32), 256, 0, stream>>>(Wqkv, wqkvt, 1024, 3072, 1024, qscale);
    conv_wt_kernel<<<dim3(32, 32), 256, 0, stream>>>(Wo, wot, 1024, 1024, 0, 1.0f);
    gemm_bt_kernel<0><<<dim3(32, 24), 256, 0, stream>>>(hb, wqkvt, qkvb, nullptr, nullptr,
                                                        4096, 3072, 1024);
    transpose_v_kernel<<<dim3(32, 32), 256, 0, stream>>>(qkvb, vt);
    attn_kernel<<<1024, 512, 0, stream>>>(qkvb, vt, attnb);
    gemm_bt_kernel<1><<<dim3(32, 8), 256, 0, stream>>>(attnb, wot, nullptr, h, xbuf,
                                                       4096, 1024, 1024);
    ln_kernel<<<4096, 256, 0, stream>>>(xbuf, gamma, beta, out);
}

// Round 16
// 116.342 us; speedup vs baseline: 1.1619x; 1.0061x over previous
//
#include <hip/hip_runtime.h>

// CONVERGED PORTFOLIO (r8 config) + attn LDS XOR-swizzle A/B (this round).
// Falsified alternatives (do not retry without new evidence):
//  - gemm1 8-phase 256x256 (r12/r14): barrier-structural stall at K=1024, 1 blk/CU.
//  - conv_h fused into gemm1 staging (r13): +6.3M bank conflicts, 57.5 us.
//  - m97 global_load_lds 2-phase (r3): -4 us vs reg-staged at K=1024.
//  - attn without LDS (r6): uncoalesced 12KB-stride lanes, 126 us.
//  - attn k-chunked LDS (r7): chunk stride bank-aligned, conflicts up 50%.
//  - attn 32x32 MFMA (r9-r11): f32x16 regs spill at w=4 cap; 1 blk/CU at w=2.

typedef unsigned short u16;
typedef unsigned int u32;
typedef __attribute__((ext_vector_type(8))) __bf16 bf16x8;
typedef __attribute__((ext_vector_type(4))) float f32x4;
typedef __attribute__((ext_vector_type(8))) unsigned short u16x8;
typedef __attribute__((ext_vector_type(4))) unsigned short u16x4;
typedef __attribute__((ext_vector_type(2))) unsigned int u32x2;
typedef __attribute__((ext_vector_type(4))) unsigned int u32x4;

#if defined(__has_builtin)
#if __has_builtin(__builtin_amdgcn_permlane32_swap) && __has_builtin(__builtin_amdgcn_permlane16_swap)
#define USE_PERMLANE 1
#endif
#endif
#ifndef USE_PERMLANE
#define USE_PERMLANE 0
#endif

__device__ __forceinline__ u16 f2bf(float f) {
    u32 u = __builtin_bit_cast(u32, f);
    u += 0x7fffu + ((u >> 16) & 1u);   // round-to-nearest-even
    return (u16)(u >> 16);
}

__device__ __forceinline__ float fexp2(float x) {
#if __has_builtin(__builtin_amdgcn_exp2f)
    return __builtin_amdgcn_exp2f(x);
#else
    return exp2f(x);
#endif
}

__device__ __forceinline__ float frcp(float x) {
#if __has_builtin(__builtin_amdgcn_rcpf)
    return __builtin_amdgcn_rcpf(x);
#else
    return 1.0f / x;
#endif
}

// ---------------- conversions ----------------
__global__ __launch_bounds__(256) void conv_h_kernel(const float* __restrict__ h,
                                                     u16* __restrict__ hb) {
    int i = blockIdx.x * 256 + threadIdx.x;
    float4 v = ((const float4*)h)[i];
    u16x4 o = { f2bf(v.x), f2bf(v.y), f2bf(v.z), f2bf(v.w) };
    ((u16x4*)hb)[i] = o;
}

// W [R][C] f32 -> Wt [C][R] bf16 (transpose + convert); rows < scale_rows get *scale
__global__ __launch_bounds__(256) void conv_wt_kernel(const float* __restrict__ W,
                                                      u16* __restrict__ Wt,
                                                      int R, int C,
                                                      int scale_rows, float scale) {
    __shared__ float tile[32][33];
    int t = threadIdx.x;
    int r = t >> 3, c4 = (t & 7) * 4;
    int gx = blockIdx.x * 32, gy = blockIdx.y * 32;
    float4 v = *(const float4*)&W[(size_t)(gy + r) * C + gx + c4];
    tile[r][c4 + 0] = v.x; tile[r][c4 + 1] = v.y;
    tile[r][c4 + 2] = v.z; tile[r][c4 + 3] = v.w;
    __syncthreads();
    float sc = (gx + r < scale_rows) ? scale : 1.0f;
    u16x4 o = { f2bf(tile[c4 + 0][r] * sc), f2bf(tile[c4 + 1][r] * sc),
                f2bf(tile[c4 + 2][r] * sc), f2bf(tile[c4 + 3][r] * sc) };
    *(u16x4*)&Wt[(size_t)(gx + r) * R + gy + c4] = o;
}

// ---------------- GEMM: C[M][N] = A[M][K] (bf16) x Bt[N][K]^T (bf16) ----------------
// reg-staged 2-phase, padded LDS (proven structure; ~570 TF at this shape)
template <int MODE>
__global__ __launch_bounds__(256) void gemm_bt_kernel(
        const u16* __restrict__ A, const u16* __restrict__ Bt,
        u16* __restrict__ Cb, const float* __restrict__ H, float* __restrict__ X,
        int M, int N, int K) {
    constexpr int LDT = 40;                 // 32 + 8 pad
    __shared__ u16 alds[2][128 * LDT];
    __shared__ u16 blds[2][128 * LDT];
    const int t = threadIdx.x;
    const int lane = t & 63;
    const int wave = t >> 6;
    const int wm = wave >> 1, wn = wave & 1;
    const int m0 = blockIdx.x * 128;
    const int n0 = blockIdx.y * 128;
    const int nk = K >> 5;

    const int srow = t >> 1;
    const int sch = (t & 1) * 2;
    const u16* ga = A + (size_t)(m0 + srow) * K + sch * 8;
    const u16* gb = Bt + (size_t)(n0 + srow) * K + sch * 8;
    const int wo = srow * LDT + sch * 8;

    u16x8 ra0 = *(const u16x8*)(ga);
    u16x8 ra1 = *(const u16x8*)(ga + 8);
    u16x8 rb0 = *(const u16x8*)(gb);
    u16x8 rb1 = *(const u16x8*)(gb + 8);
    *(u16x8*)&alds[0][wo] = ra0;  *(u16x8*)&alds[0][wo + 8] = ra1;
    *(u16x8*)&blds[0][wo] = rb0;  *(u16x8*)&blds[0][wo + 8] = rb1;

    f32x4 acc[4][4] = {};
    const int ko = (lane >> 4) * 8;
    const int arow_base = wm * 64 + (lane & 15);
    const int brow_base = wn * 64 + (lane & 15);

    int cur = 0;
    for (int kt = 0; kt < nk; ++kt) {
        __syncthreads();
        if (kt + 1 < nk) {
            const u16* gan = ga + (kt + 1) * 32;
            const u16* gbn = gb + (kt + 1) * 32;
            ra0 = *(const u16x8*)(gan);
            ra1 = *(const u16x8*)(gan + 8);
            rb0 = *(const u16x8*)(gbn);
            rb1 = *(const u16x8*)(gbn + 8);
        }
        bf16x8 afrag[4], bfrag[4];
#pragma unroll
        for (int m = 0; m < 4; ++m)
            afrag[m] = *(const bf16x8*)&alds[cur][(arow_base + m * 16) * LDT + ko];
#pragma unroll
        for (int n = 0; n < 4; ++n)
            bfrag[n] = *(const bf16x8*)&blds[cur][(brow_base + n * 16) * LDT + ko];
#pragma unroll
        for (int m = 0; m < 4; ++m)
#pragma unroll
            for (int n = 0; n < 4; ++n)
                acc[m][n] = __builtin_amdgcn_mfma_f32_16x16x32_bf16(afrag[m], bfrag[n],
                                                                   acc[m][n], 0, 0, 0);
        if (kt + 1 < nk) {
            *(u16x8*)&alds[cur ^ 1][wo] = ra0;  *(u16x8*)&alds[cur ^ 1][wo + 8] = ra1;
            *(u16x8*)&blds[cur ^ 1][wo] = rb0;  *(u16x8*)&blds[cur ^ 1][wo + 8] = rb1;
        }
        cur ^= 1;
    }

#pragma unroll
    for (int m = 0; m < 4; ++m)
#pragma unroll
        for (int n = 0; n < 4; ++n)
#pragma unroll
            for (int r = 0; r < 4; ++r) {
                int row = m0 + wm * 64 + m * 16 + (lane >> 4) * 4 + r;
                int col = n0 + wn * 64 + n * 16 + (lane & 15);
                size_t idx = (size_t)row * N + col;
                if (MODE == 0) Cb[idx] = f2bf(acc[m][n][r]);
                else           X[idx] = acc[m][n][r] + H[idx];
            }
}

// ---------------- V transpose ----------------
__global__ __launch_bounds__(256) void transpose_v_kernel(const u16* __restrict__ qkvb,
                                                          u16* __restrict__ vt) {
    __shared__ u16 tl[64][72];
    const int t = threadIdx.x;
    const int p = blockIdx.y;
    const int nn = p >> 1, b = p & 1;
    const int s0 = blockIdx.x * 64;
    const int r = t >> 2;
    const int ch = (t & 3) * 2;
    const u16* g = qkvb + ((size_t)(s0 + r) * 2 + b) * 3072 + 2048 + nn * 64;
    *(u16x8*)&tl[r][ch * 8]     = *(const u16x8*)(g + ch * 8);
    *(u16x8*)&tl[r][ch * 8 + 8] = *(const u16x8*)(g + ch * 8 + 8);
    __syncthreads();
    const int dh = t >> 2;
    const int sc = (t & 3) * 2;
    u16* o = vt + ((size_t)p * 64 + dh) * 2048 + s0;
#pragma unroll
    for (int q = 0; q < 2; ++q) {
        int scq = sc + q;
        u16x8 v;
#pragma unroll
        for (int j = 0; j < 8; ++j) v[j] = tl[scq * 8 + j][dh];
        *(u16x8*)(o + scq * 8) = v;
    }
}

// ---------------- causal flash attention (split-j, 8 waves, XOR-swz LDS) ----------
// r8 structure; LDS layout changed from [64][72] pad to [64][64] with 16B-slot
// XOR swizzle (slot ^= row&7) on BOTH staging writes and fragment reads (G4).
__global__ __launch_bounds__(512) void attn_kernel(const u16* __restrict__ qkvb,
                                                   const u16* __restrict__ vt,
                                                   u16* __restrict__ attnb) {
    __shared__ u16 kvs[2][2][2][4096];    // [group][buf][K/V][row*64 + swz col]
#if !USE_PERMLANE
    __shared__ u16 plds[8][16 * 72];
#endif
    const int t = threadIdx.x;
    const int lane = t & 63;
    const int w = (t >> 6) & 3;           // wave within group
    const int grp = t >> 8;               // 0: even jt, 1: odd jt
    const int bid = blockIdx.x;
    const int qt = 31 - (bid >> 5);       // heavy q-tiles dispatched first
    const int p = bid & 31;
    const int nn = p >> 1, b = p & 1;
    const int i0 = qt * 64;

    const int li = lane & 15;
    const int lg = lane >> 4;

    // Q fragments (B-operand rows i = i0 + w*16 + li) — identical for both groups
    const int qrow = i0 + w * 16 + li;
    const u16* qg = qkvb + ((size_t)qrow * 2 + b) * 3072 + nn * 64 + lg * 8;
    bf16x8 qa0 = *(const bf16x8*)(qg);
    bf16x8 qa1 = *(const bf16x8*)(qg + 32);

    f32x4 o[4] = {};                      // O[row = lg*4+r][d = cf*16+li]
    float mrun = -3.0e38f;
    float lrun = 0.f;

    // staging geometry (group-local 256 threads); swizzled 16B-slot offsets
    const int tg = t & 255;
    const int srow = tg >> 2;             // 0..63
    const int sch = (tg & 3) * 2;         // slots {sch, sch+1}
    const u16* kg = qkvb + 1024 + nn * 64 + sch * 8;
    const u16* vg = vt + ((size_t)p * 64 + srow) * 2048 + sch * 8;
    const int swo0 = srow * 64 + ((sch ^ (srow & 7)) << 3);
    const int swo1 = srow * 64 + (((sch + 1) ^ (srow & 7)) << 3);

    // fragment-read swizzled slot offsets (row & 7 == li & 7 since base % 16 == 0)
    const int rsk0 = (lg ^ (li & 7)) << 3;          // QK^T cols [lg*8 .. )
    const int rsk1 = ((4 + lg) ^ (li & 7)) << 3;    // QK^T cols [32+lg*8 .. )

    const int nt = qt + 1;
    const int G = (nt + 1) >> 1;          // rounds per group

    u16x8 k0, k1, v0, v1;
    if (grp < nt) {                       // stage my first tile (jt = grp)
        const u16* kgp = kg + ((size_t)(grp * 64 + srow) * 2 + b) * 3072;
        k0 = *(const u16x8*)(kgp);  k1 = *(const u16x8*)(kgp + 8);
        const u16* vgp = vg + grp * 64;
        v0 = *(const u16x8*)(vgp);  v1 = *(const u16x8*)(vgp + 8);
        *(u16x8*)&kvs[grp][0][0][swo0] = k0;  *(u16x8*)&kvs[grp][0][0][swo1] = k1;
        *(u16x8*)&kvs[grp][0][1][swo0] = v0;  *(u16x8*)&kvs[grp][0][1][swo1] = v1;
    }
    __syncthreads();

    for (int s = 0; s < G; ++s) {
        const int jt = 2 * s + grp;
        const int buf = s & 1;
        const bool active = jt < nt;      // only group 1's last round can be inactive
        if (jt + 2 < nt) {                // issue-early my next tile
            const u16* kgp = kg + ((size_t)((jt + 2) * 64 + srow) * 2 + b) * 3072;
            k0 = *(const u16x8*)(kgp);  k1 = *(const u16x8*)(kgp + 8);
            const u16* vgp = vg + (jt + 2) * 64;
            v0 = *(const u16x8*)(vgp);  v1 = *(const u16x8*)(vgp + 8);
        }

        if (active) {
            const u16* kl = &kvs[grp][buf][0][0];
            const u16* vl = &kvs[grp][buf][1][0];

            // swapped QK^T: st[cf][r] = S^T[j = jt*64+cf*16+lg*4+r][i = i0+w*16+li]
            f32x4 st[4];
            __builtin_amdgcn_s_setprio(1);
#pragma unroll
            for (int cf = 0; cf < 4; ++cf) {
                bf16x8 kb0 = *(const bf16x8*)&kl[(cf * 16 + li) * 64 + rsk0];
                bf16x8 kb1 = *(const bf16x8*)&kl[(cf * 16 + li) * 64 + rsk1];
                f32x4 z = {};
                z = __builtin_amdgcn_mfma_f32_16x16x32_bf16(kb0, qa0, z, 0, 0, 0);
                z = __builtin_amdgcn_mfma_f32_16x16x32_bf16(kb1, qa1, z, 0, 0, 0);
                st[cf] = z;
            }
            __builtin_amdgcn_s_setprio(0);

            if (jt == qt) {               // mask only the diagonal tile
                const int it = w * 16 + li;
#pragma unroll
                for (int cf = 0; cf < 4; ++cf)
#pragma unroll
                    for (int r = 0; r < 4; ++r) {
                        int jl = cf * 16 + lg * 4 + r;
                        if (jl > it) st[cf][r] = -3.0e38f;
                    }
            }

            // row max: 15 in-reg + 2 shuffles
            float mloc = st[0][0];
#pragma unroll
            for (int cf = 0; cf < 4; ++cf)
#pragma unroll
                for (int r = 0; r < 4; ++r) mloc = fmaxf(mloc, st[cf][r]);
            mloc = fmaxf(mloc, __shfl_xor(mloc, 16, 64));
            mloc = fmaxf(mloc, __shfl_xor(mloc, 32, 64));

            // defer-rescale (T13)
            if (__any(mloc > mrun + 8.0f)) {
                float mnew = fmaxf(mrun, mloc);
                float alpha = fexp2(mrun - mnew);
                lrun *= alpha;
                mrun = mnew;
#pragma unroll
                for (int r = 0; r < 4; ++r) {
                    float ar = __shfl(alpha, lg * 4 + r, 64);
#pragma unroll
                    for (int cf = 0; cf < 4; ++cf) o[cf][r] *= ar;
                }
            }

#if USE_PERMLANE
            float rsum = 0.f;
            u32 wv[4][2];
#pragma unroll
            for (int cf = 0; cf < 4; ++cf)
#pragma unroll
                for (int rr = 0; rr < 2; ++rr) {
                    float p0 = fexp2(st[cf][2 * rr] - mrun);
                    float p1 = fexp2(st[cf][2 * rr + 1] - mrun);
                    rsum += p0 + p1;
                    u32 wres;
                    asm("v_cvt_pk_bf16_f32 %0, %1, %2" : "=v"(wres) : "v"(p0), "v"(p1));
                    wv[cf][rr] = wres;
                }
            rsum += __shfl_xor(rsum, 16, 64);
            rsum += __shfl_xor(rsum, 32, 64);
            lrun += rsum;

            __builtin_amdgcn_s_setprio(1);
#pragma unroll
            for (int ks = 0; ks < 2; ++ks) {
                u32x2 sa = __builtin_amdgcn_permlane32_swap(wv[2 * ks][0], wv[2 * ks + 1][0], false, false);
                u32x2 fa = __builtin_amdgcn_permlane16_swap(sa[0], sa[1], false, false);
                u32x2 sb = __builtin_amdgcn_permlane32_swap(wv[2 * ks][1], wv[2 * ks + 1][1], false, false);
                u32x2 fb = __builtin_amdgcn_permlane16_swap(sb[0], sb[1], false, false);
                u32x4 fw = { fa[0], fb[0], fa[1], fb[1] };
                bf16x8 pa = __builtin_bit_cast(bf16x8, fw);
#pragma unroll
                for (int cf = 0; cf < 4; ++cf) {
                    bf16x8 vb = *(const bf16x8*)&vl[(cf * 16 + li) * 64
                                                    + (((ks * 4 + lg) ^ (li & 7)) << 3)];
                    o[cf] = __builtin_amdgcn_mfma_f32_16x16x32_bf16(pa, vb, o[cf], 0, 0, 0);
                }
            }
            __builtin_amdgcn_s_setprio(0);
#else
            float rsum = 0.f;
#pragma unroll
            for (int cf = 0; cf < 4; ++cf) {
                u16x4 pw;
#pragma unroll
                for (int r = 0; r < 4; ++r) {
                    float pv = fexp2(st[cf][r] - mrun);
                    rsum += pv;
                    pw[r] = f2bf(pv);
                }
                *(u16x4*)&plds[t >> 6][li * 72 + cf * 16 + lg * 4] = pw;
            }
            rsum += __shfl_xor(rsum, 16, 64);
            rsum += __shfl_xor(rsum, 32, 64);
            lrun += rsum;

            asm volatile("s_waitcnt lgkmcnt(0)" ::: "memory");
            __builtin_amdgcn_sched_barrier(0);

#pragma unroll
            for (int ks = 0; ks < 2; ++ks) {
                bf16x8 pa = *(const bf16x8*)&plds[t >> 6][li * 72 + ks * 32 + lg * 8];
#pragma unroll
                for (int cf = 0; cf < 4; ++cf) {
                    bf16x8 vb = *(const bf16x8*)&vl[(cf * 16 + li) * 64
                                                    + (((ks * 4 + lg) ^ (li & 7)) << 3)];
                    o[cf] = __builtin_amdgcn_mfma_f32_16x16x32_bf16(pa, vb, o[cf], 0, 0, 0);
                }
            }
#endif
        }

        if (jt + 2 < nt) {                // write-late my next tile into other buffer
            *(u16x8*)&kvs[grp][buf ^ 1][0][swo0] = k0;  *(u16x8*)&kvs[grp][buf ^ 1][0][swo1] = k1;
            *(u16x8*)&kvs[grp][buf ^ 1][1][swo0] = v0;  *(u16x8*)&kvs[grp][buf ^ 1][1][swo1] = v1;
        }
        __syncthreads();
    }

    // ---- merge group partials (online-softmax combine) ----
    float* osc = (float*)&kvs[1][0][0][0];       // [64 rows][65] f32 (raw scratch)
    float* msc = osc + 64 * 65;                  // [64]
    float* lsc = msc + 64;                       // [64]
    if (grp == 1) {
#pragma unroll
        for (int cf = 0; cf < 4; ++cf)
#pragma unroll
            for (int r = 0; r < 4; ++r)
                osc[(w * 16 + lg * 4 + r) * 65 + cf * 16 + li] = o[cf][r];
        if (lg == 0) { msc[w * 16 + li] = mrun; lsc[w * 16 + li] = lrun; }
    }
    __syncthreads();
    if (grp == 0) {
        float mB = msc[w * 16 + li];
        float lB = lsc[w * 16 + li];
        float m = fmaxf(mrun, mB);
        float eA = fexp2(mrun - m);
        float eB = fexp2(mB - m);
        float linv = frcp(lrun * eA + lB * eB);
#pragma unroll
        for (int r = 0; r < 4; ++r) {
            float eAr = __shfl(eA, lg * 4 + r, 64);
            float eBr = __shfl(eB, lg * 4 + r, 64);
            float rvr = __shfl(linv, lg * 4 + r, 64);
            int row = i0 + w * 16 + lg * 4 + r;
            u16* og = attnb + ((size_t)row * 2 + b) * 1024 + nn * 64;
#pragma unroll
            for (int cf = 0; cf < 4; ++cf) {
                float ob = osc[(w * 16 + lg * 4 + r) * 65 + cf * 16 + li];
                og[cf * 16 + li] = f2bf((o[cf][r] * eAr + ob * eBr) * rvr);
            }
        }
    }
}

// ---------------- residual LayerNorm ----------------
__global__ __launch_bounds__(256) void ln_kernel(const float* __restrict__ X,
                                                 const float* __restrict__ gamma,
                                                 const float* __restrict__ beta,
                                                 float* __restrict__ out) {
    __shared__ float red[8];
    const int t = threadIdx.x;
    const int row = blockIdx.x;
    float4 v = ((const float4*)(X + (size_t)row * 1024))[t];
    float s = v.x + v.y + v.z + v.w;
#pragma unroll
    for (int off = 1; off < 64; off <<= 1) s += __shfl_xor(s, off, 64);
    if ((t & 63) == 0) red[t >> 6] = s;
    __syncthreads();
    float mu = (red[0] + red[1] + red[2] + red[3]) * (1.f / 1024.f);
    float dx = v.x - mu, dy = v.y - mu, dz = v.z - mu, dw = v.w - mu;
    float q = dx * dx + dy * dy + dz * dz + dw * dw;
#pragma unroll
    for (int off = 1; off < 64; off <<= 1) q += __shfl_xor(q, off, 64);
    if ((t & 63) == 0) red[4 + (t >> 6)] = q;
    __syncthreads();
    float var = (red[4] + red[5] + red[6] + red[7]) * (1.f / 1024.f);
    float rs = rsqrtf(var + 1e-5f);
    float4 g = ((const float4*)gamma)[t];
    float4 bt = ((const float4*)beta)[t];
    float4 o;
    o.x = dx * rs * g.x + bt.x;
    o.y = dy * rs * g.y + bt.y;
    o.z = dz * rs * g.z + bt.z;
    o.w = dw * rs * g.w + bt.w;
    ((float4*)(out + (size_t)row * 1024))[t] = o;
}

// ---------------- launch ----------------
extern "C" void kernel_launch(void* const* d_in, const int* in_sizes, int n_in,
                              void* d_out, int out_size, void* d_ws, size_t ws_size,
                              hipStream_t stream) {
    const float* h     = (const float*)d_in[0];
    // d_in[1] = attn_mask (deterministic causal triu; applied analytically)
    const float* Wqkv  = (const float*)d_in[2];
    const float* Wo    = (const float*)d_in[3];
    const float* gamma = (const float*)d_in[4];
    const float* beta  = (const float*)d_in[5];
    float* out = (float*)d_out;

    char* ws = (char*)d_ws;
    u16*   hb    = (u16*)(ws);
    u16*   wqkvt = (u16*)(ws + 8388608);
    u16*   wot   = (u16*)(ws + 14680064);
    u16*   qkvb  = (u16*)(ws + 16777216);
    u16*   vt    = (u16*)(ws + 41943040);
    u16*   attnb = (u16*)(ws + 50331648);
    float* xbuf  = (float*)(ws + 58720256);

    const float qscale = 0.125f * 1.44269504088896f;  // 1/sqrt(Dh) * log2(e)

    conv_h_kernel<<<4096, 256, 0, stream>>>(h, hb);
    conv_wt_kernel<<<dim3(96, 32), 256, 0, stream>>>(Wqkv, wqkvt, 1024, 3072, 1024, qscale);
    conv_wt_kernel<<<dim3(32, 32), 256, 0, stream>>>(Wo, wot, 1024, 1024, 0, 1.0f);
    gemm_bt_kernel<0><<<dim3(32, 24), 256, 0, stream>>>(hb, wqkvt, qkvb, nullptr, nullptr,
                                                        4096, 3072, 1024);
    transpose_v_kernel<<<dim3(32, 32), 256, 0, stream>>>(qkvb, vt);
    attn_kernel<<<1024, 512, 0, stream>>>(qkvb, vt, attnb);
    gemm_bt_kernel<1><<<dim3(32, 8), 256, 0, stream>>>(attnb, wot, nullptr, h, xbuf,
                                                       4096, 1024, 1024);
    ln_kernel<<<4096, 256, 0, stream>>>(xbuf, gamma, beta, out);
}